// Round 10
// baseline (7205.419 us; speedup 1.0000x reference)
//
#include <hip/hip_runtime.h>
#include <math.h>
#include <stdint.h>

#define B_   64
#define S_   255
#define SP   256
#define D_   512
#define H_   8
#define L_   6
#define FF_  2048
#define HID_ 256
#define N_   (B_*SP)       // 16384 rows
#define EPS  1e-5f

using bf16x8 = __bf16 __attribute__((ext_vector_type(8)));
using f32x4  = float __attribute__((ext_vector_type(4)));
using u16x4  = unsigned short __attribute__((ext_vector_type(4)));

// ---------------------------------------------------------------- utilities
__device__ inline float wave_sum(float v) {
#pragma unroll
    for (int off = 32; off; off >>= 1) v += __shfl_xor(v, off);
    return v;
}

// fast exact-erf gelu: A&S 7.1.26 polynomial, |erf err| <= 1.5e-7
__device__ inline float gelu_exact(float x) {
    float z  = fabsf(x) * 0.70710678118654752f;
    float tt = __builtin_amdgcn_rcpf(fmaf(0.3275911f, z, 1.0f));
    float poly = tt * (0.254829592f + tt * (-0.284496736f + tt * (1.421413741f +
                 tt * (-1.453152027f + tt * 1.061405429f))));
    float er = 1.0f - poly * __expf(-z * z);
    er = copysignf(er, x);
    return 0.5f * x * (1.0f + er);
}

__device__ inline unsigned short bf_bits(float x) {
    __bf16 h = (__bf16)x;
    return *(unsigned short*)&h;
}

__device__ inline float bf_val(unsigned short u) {
    __bf16 h = *(__bf16*)&u;
    return (float)h;
}

// fp8 e4m3fn encode (RNE) / decode
__device__ inline uint8_t enc_e4m3(float f) {
    uint32_t u = __float_as_uint(f);
    uint32_t s = (u >> 24) & 0x80u;
    float a = fabsf(f);
    if (a < 0.015625f) {
        int m = (int)rintf(a * 512.0f);
        if (m >= 8) return (uint8_t)(s | 0x08);
        return (uint8_t)(s | (uint32_t)m);
    }
    if (a > 448.0f) return (uint8_t)(s | 0x7E);
    uint32_t b = __float_as_uint(a);
    uint32_t expf_ = b >> 23;
    uint32_t mant = b & 0x7FFFFF;
    uint32_t keep = mant >> 20;
    uint32_t rest = mant & 0xFFFFF;
    if (rest > 0x80000u || (rest == 0x80000u && (keep & 1))) keep++;
    if (keep == 8) { keep = 0; expf_++; }
    int e8 = (int)expf_ - 120;
    if (e8 >= 16) return (uint8_t)(s | 0x7E);
    return (uint8_t)(s | ((uint32_t)e8 << 3) | keep);
}

__device__ inline float dec_e4m3(uint32_t b) {
    uint32_t mag = b & 0x7Fu;
    float fm = __uint_as_float((mag << 20) + (120u << 23));
    if ((mag >> 3) == 0) fm = fm * 2.0f - 0.015625f;
    return (b & 0x80u) ? -fm : fm;
}

// async global->LDS 16B (m97 recipe)
#define GLOAD16(gsrc, ldst) \
    __builtin_amdgcn_global_load_lds((const __attribute__((address_space(1))) unsigned int*)(gsrc), \
                                     (__attribute__((address_space(3))) unsigned int*)(ldst), 16, 0, 0)

// ---------------------------------------------------------------- build Xb = [cls; atom] (bf16 trunk)
__global__ void k_build_x(const float* __restrict__ atom, const float* __restrict__ cls,
                          __bf16* __restrict__ Xb) {
    int idx = blockIdx.x * 256 + threadIdx.x;
    int col = idx & (D_ - 1);
    int row = idx >> 9;
    int sr  = row & (SP - 1);
    int b   = row >> 8;
    float v = (sr == 0) ? cls[col] : atom[((size_t)(b * S_) + (sr - 1)) * D_ + col];
    Xb[idx] = (__bf16)v;
}

// ---------------------------------------------------------------- mask layout detection
__global__ void k_mask_detect(const unsigned int* __restrict__ mw, int nw, int* flag) {
    int i = blockIdx.x * 256 + threadIdx.x;
    if (i < nw && mw[i] > 1u) atomicOr(flag, 1);
}

__global__ void k_mask_prep(const void* __restrict__ mraw, const int* __restrict__ flag,
                            float* __restrict__ mskadd) {
    int i = blockIdx.x * 256 + threadIdx.x;
    int b = i >> 8, j = i & 255;
    float v = 0.0f;
    if (j > 0) {
        int src = b * S_ + (j - 1);
        bool m = (*flag) ? (((const unsigned char*)mraw)[src] != 0)
                         : (((const int*)mraw)[src] != 0);
        if (m) v = -1e30f;
    }
    mskadd[i] = v;
}

// ---------------------------------------------------------------- weight transpose+cast
__global__ __launch_bounds__(256) void k_wt(const float* __restrict__ W, __bf16* __restrict__ Wt,
                                            int K, int Mw, int mout_off,
                                            size_t in_lstride, size_t out_lstride) {
    __shared__ float T[64][65];
    int l = blockIdx.z;
    int m0 = blockIdx.x * 64, k0 = blockIdx.y * 64;
    const float* Wl = W + (size_t)l * in_lstride;
    __bf16* Wtl = Wt + (size_t)l * out_lstride;
    int tid = threadIdx.x;
    int cc = tid & 63, rr = tid >> 6;
#pragma unroll
    for (int p = 0; p < 16; p++) {
        int kk = rr + p * 4;
        T[kk][cc] = Wl[(size_t)(k0 + kk) * Mw + m0 + cc];
    }
    __syncthreads();
#pragma unroll
    for (int p = 0; p < 16; p++) {
        int mm = rr + p * 4;
        Wtl[(size_t)(mout_off + m0 + mm) * K + k0 + cc] = (__bf16)T[cc][mm];
    }
}

// ---------------------------------------------------------------- qkv bias concat
__global__ void k_bcat(const float* __restrict__ bq, const float* __restrict__ bk,
                       const float* __restrict__ bv, float* __restrict__ bqkv) {
    int i = blockIdx.x * 256 + threadIdx.x;
    int l = i / 1536, c = i % 1536;
    float v;
    if (c < 512)       v = bq[l * 512 + c];
    else if (c < 1024) v = bk[l * 512 + c - 512];
    else               v = bv[l * 512 + c - 1024];
    bqkv[i] = v;
}

// ---------------------------------------------------------------- bias repack, coalesced both sides
__global__ __launch_bounds__(256) void k_ebt5(const float* __restrict__ eb, uint8_t* __restrict__ ebt) {
    __shared__ uint8_t Ls[8 * 16 * 260];           // [h][qi][260], odd-dword qi stride
    int blk = blockIdx.x;                          // 64*16
    int b = blk >> 4, wm = blk & 15;
    int w = wm >> 2, mq = wm & 3;
    int qbase = w * 64 + mq * 16;
    int t = threadIdx.x;
    for (int qi = 0; qi < 16; qi++) {
        int q = qbase + qi;
        if (q > 0) {
            const float4* src = (const float4*)(eb + ((size_t)(b * 255) + (q - 1)) * 2040);
#pragma unroll
            for (int p = 0; p < 2; p++) {
                int idx4 = t + p * 256;
                if (idx4 < 510) {
                    float4 v = src[idx4];
                    int k  = idx4 >> 1;
                    int h0 = (idx4 & 1) * 4;
                    Ls[((h0 + 0) * 16 + qi) * 260 + k] = enc_e4m3(v.x);
                    Ls[((h0 + 1) * 16 + qi) * 260 + k] = enc_e4m3(v.y);
                    Ls[((h0 + 2) * 16 + qi) * 260 + k] = enc_e4m3(v.z);
                    Ls[((h0 + 3) * 16 + qi) * 260 + k] = enc_e4m3(v.w);
                }
            }
        }
    }
    __syncthreads();
    int cc = t >> 4, qi = t & 15;
    int q = qbase + qi;
    uint32_t* outp = (uint32_t*)ebt;
#pragma unroll
    for (int h = 0; h < 8; h++) {
#pragma unroll
        for (int tl = 0; tl < 4; tl++) {
            uint32_t d = 0;
            if (q > 0) {
#pragma unroll
                for (int nk = 0; nk < 4; nk++) {
                    int k = tl * 64 + nk * 16 + cc;
                    if (k > 0) d |= (uint32_t)Ls[(h * 16 + qi) * 260 + (k - 1)] << (nk * 8);
                }
            }
            size_t x = ((((size_t)(b * 8 + h) * 4 + tl) * 4 + w) * 4 + mq) * 256 + t;
            outp[x] = d;
        }
    }
}

// ---------------------------------------------------------------- 128x128 single-buffer MFMA GEMM
// m97 recipe at BK=64: 32 KB LDS -> 4-5 blocks/CU; cross-block TLP (m114) covers the
// per-tile vmcnt/barrier drains. T1 XCD swizzle; T2 both-sides XOR involution; T5 setprio.
template<int GELU>
__global__ __launch_bounds__(256, 5) void k_gemm2(const __bf16* __restrict__ Ag,
                                                  const __bf16* __restrict__ Bg,
                                                  const float* __restrict__ bias,
                                                  __bf16* __restrict__ Cb,
                                                  __bf16* __restrict__ vtout,
                                                  int K, int M, int gx) {
    __shared__ __align__(16) __bf16 AS[128 * 64];
    __shared__ __align__(16) __bf16 BS[128 * 64];
    const int tid = threadIdx.x;
    const int w = tid >> 6, lane = tid & 63;
    const int wr = w >> 1, wc = w & 1;
    const int lrow = lane & 15, lg = lane >> 4;
    const int nwg = gridDim.x, bid = blockIdx.x;
    const int swz = (bid & 7) * (nwg >> 3) + (bid >> 3);   // T1 (nwg % 8 == 0)
    const int by = swz / gx, bx = swz - by * gx;
    const int rowbase = by * 128, colbase = bx * 128;
    const int nkt = K >> 6;

    f32x4 acc[4][4];
#pragma unroll
    for (int m = 0; m < 4; m++)
#pragma unroll
        for (int n = 0; n < 4; n++) acc[m][n] = f32x4{0.f, 0.f, 0.f, 0.f};

    for (int kt = 0; kt < nkt; ++kt) {
        if (kt) __builtin_amdgcn_s_barrier();      // prior tile's ds_reads done
        __builtin_amdgcn_sched_barrier(0);
#pragma unroll
        for (int p = 0; p < 4; p++) {
            int s = tid + p * 256;                 // 1024 slots of 16B
            int row = s >> 3, sg = s & 7;
            GLOAD16(Ag + (size_t)(rowbase + row) * K + kt * 64 + ((sg ^ (row & 7)) << 3), &AS[s * 8]);
            GLOAD16(Bg + (size_t)(colbase + row) * K + kt * 64 + ((sg ^ (row & 7)) << 3), &BS[s * 8]);
        }
        asm volatile("s_waitcnt vmcnt(0)" ::: "memory");
        __builtin_amdgcn_s_barrier();

        bf16x8 aF[4][2], bF[4][2];
#pragma unroll
        for (int m = 0; m < 4; m++) {
            int arow = wr * 64 + m * 16 + lrow;
#pragma unroll
            for (int ks = 0; ks < 2; ks++) {
                int sl = (lg + ks * 4) ^ (arow & 7);
                aF[m][ks] = *(const bf16x8*)&AS[arow * 64 + sl * 8];
            }
        }
#pragma unroll
        for (int n = 0; n < 4; n++) {
            int brow = wc * 64 + n * 16 + lrow;
#pragma unroll
            for (int ks = 0; ks < 2; ks++) {
                int sl = (lg + ks * 4) ^ (brow & 7);
                bF[n][ks] = *(const bf16x8*)&BS[brow * 64 + sl * 8];
            }
        }
        asm volatile("s_waitcnt lgkmcnt(0)" ::: "memory");
        __builtin_amdgcn_sched_barrier(0);         // rule #18
        __builtin_amdgcn_s_setprio(1);
#pragma unroll
        for (int m = 0; m < 4; m++)
#pragma unroll
            for (int n = 0; n < 4; n++)
#pragma unroll
                for (int ks = 0; ks < 2; ks++)
                    acc[m][n] = __builtin_amdgcn_mfma_f32_16x16x32_bf16(aF[m][ks], bF[n][ks],
                                                                        acc[m][n], 0, 0, 0);
        __builtin_amdgcn_s_setprio(0);
    }

    // ---- epilogue (bf16 out; V^T split for QKV) ----
    const bool dovt = (vtout != nullptr) && (colbase >= 1024);   // block-uniform
#pragma unroll
    for (int m = 0; m < 4; m++) {
        int row = rowbase + wr * 64 + m * 16 + lg * 4;
#pragma unroll
        for (int n = 0; n < 4; n++) {
            int col = colbase + wc * 64 + n * 16 + lrow;
            float bv = bias ? bias[col] : 0.0f;
            float v[4];
#pragma unroll
            for (int r = 0; r < 4; r++) {
                float x = acc[m][n][r] + bv;
                if (GELU) x = gelu_exact(x);
                v[r] = x;
            }
            if (dovt) {
                int hcol = col - 1024;
                int hh = hcol >> 6, d = hcol & 63;
                int bb = row >> 8, s0 = row & 255;
                u16x4 pk = { bf_bits(v[0]), bf_bits(v[1]), bf_bits(v[2]), bf_bits(v[3]) };
                *(u16x4*)&vtout[((size_t)((bb * 8 + hh) * 64 + d)) * 256 + s0] = pk;
            } else {
#pragma unroll
                for (int r = 0; r < 4; r++)
                    Cb[(size_t)(row + r) * M + col] = (__bf16)v[r];
            }
        }
    }
}

// ---------------------------------------------------------------- MFMA fused attention
// grid: 2048 blocks, XCD-swizzled. Monotone key mask -> block-uniform skip of fully-masked tiles.
__global__ __launch_bounds__(256) void k_attn(const __bf16* __restrict__ QKV,
                                              const uint8_t* __restrict__ ebt,
                                              const float* __restrict__ mskadd,
                                              const __bf16* __restrict__ Vt,
                                              __bf16* __restrict__ T) {
    __shared__ __align__(16) char Ks[8192];
    __shared__ __align__(16) char Vs[8192];
    __shared__ __align__(16) char Ps[4][2048];
    __shared__ float Ma[256];
    const int bid = blockIdx.x;
    const int swzb = (bid & 7) * 256 + (bid >> 3);     // T1, nwg = 2048
    const int bh = swzb >> 2, qt = swzb & 3;
    const int b = bh >> 3, h = bh & 7;
    const int tid = threadIdx.x, wid = tid >> 6, lane = tid & 63;
    const int g = lane >> 4, c = lane & 15;

    Ma[tid] = mskadd[(b << 8) + tid];

    bf16x8 qf[2];
    {
        const __bf16* qrow = QKV + (size_t)((b << 8) + qt * 64 + wid * 16 + c) * 1536 + h * 64;
        qf[0] = *(const bf16x8*)(qrow + g * 8);
        qf[1] = *(const bf16x8*)(qrow + 32 + g * 8);
    }

    f32x4 oacc[4];
    float m_s[4], l_s[4];
#pragma unroll
    for (int r = 0; r < 4; r++) { m_s[r] = -1e30f; l_s[r] = 0.0f; }
#pragma unroll
    for (int nd = 0; nd < 4; nd++) oacc[nd] = f32x4{0.f, 0.f, 0.f, 0.f};

    for (int t = 0; t < 4; t++) {
        const int t0 = t * 64;
        __syncthreads();
        if (t0 > 0 && Ma[t0] < -0.5f) continue;    // monotone mask: whole tile masked
#pragma unroll
        for (int p = 0; p < 2; p++) {
            int idx = tid + p * 256;
            int row = idx >> 3, c8 = idx & 7;
            int lds = row * 128 + ((c8 * 16) ^ ((row & 7) << 4));
            *(uint4*)(Ks + lds) = *(const uint4*)&QKV[(size_t)((b << 8) + t0 + row) * 1536 + 512 + h * 64 + c8 * 8];
            *(uint4*)(Vs + lds) = *(const uint4*)&Vt[((size_t)bh * 64 + row) * 256 + t0 + c8 * 8];
        }
        __syncthreads();

        bf16x8 kf[4][2], vb[4][2];
#pragma unroll
        for (int n = 0; n < 4; n++) {
            int row = n * 16 + c;
#pragma unroll
            for (int ks = 0; ks < 2; ks++) {
                int col = (g * 16 + ks * 64) ^ ((row & 7) << 4);
                kf[n][ks] = *(const bf16x8*)(Ks + row * 128 + col);
                vb[n][ks] = *(const bf16x8*)(Vs + row * 128 + col);
            }
        }

        f32x4 sa[4];
#pragma unroll
        for (int nk = 0; nk < 4; nk++) sa[nk] = f32x4{0.f, 0.f, 0.f, 0.f};
#pragma unroll
        for (int ks = 0; ks < 2; ks++)
#pragma unroll
            for (int nk = 0; nk < 4; nk++)
                sa[nk] = __builtin_amdgcn_mfma_f32_16x16x32_bf16(qf[ks], kf[nk][ks], sa[nk], 0, 0, 0);

        uint4 b4 = *(const uint4*)(ebt + ((((size_t)bh * 4 + t) * 4 + qt) * 4 + wid) * 1024 + c * 64 + g * 16);
        uint32_t bw[4] = { b4.x, b4.y, b4.z, b4.w };
        float s[4][4];                             // [nk][r]
#pragma unroll
        for (int nk = 0; nk < 4; nk++) {
            float ma = Ma[t0 + nk * 16 + c];
#pragma unroll
            for (int r = 0; r < 4; r++)
                s[nk][r] = sa[nk][r] * 0.125f + dec_e4m3((bw[r] >> (nk * 8)) & 0xFF) + ma;
        }

        float corr[4];
#pragma unroll
        for (int r = 0; r < 4; r++) {
            float tm = fmaxf(fmaxf(s[0][r], s[1][r]), fmaxf(s[2][r], s[3][r]));
#pragma unroll
            for (int off = 1; off < 16; off <<= 1)
                tm = fmaxf(tm, __shfl_xor(tm, off));
            float mnew = fmaxf(m_s[r], tm);
            corr[r] = __expf(m_s[r] - mnew);
            m_s[r] = mnew;
            float psum = 0.0f;
#pragma unroll
            for (int nk = 0; nk < 4; nk++) {
                s[nk][r] = __expf(s[nk][r] - mnew);
                psum += s[nk][r];
            }
#pragma unroll
            for (int off = 1; off < 16; off <<= 1)
                psum += __shfl_xor(psum, off);
            l_s[r] = l_s[r] * corr[r] + psum;
        }
#pragma unroll
        for (int nd = 0; nd < 4; nd++)
#pragma unroll
            for (int r = 0; r < 4; r++)
                oacc[nd][r] *= corr[r];

        char* psw = Ps[wid];
#pragma unroll
        for (int r = 0; r < 4; r++) {
            int qs = g * 4 + r;
#pragma unroll
            for (int nk = 0; nk < 4; nk++)
                *(__bf16*)(psw + qs * 128 + ((nk * 32 + c * 2) ^ ((qs & 7) << 4))) = (__bf16)s[nk][r];
        }
        bf16x8 pa[2];
#pragma unroll
        for (int ks = 0; ks < 2; ks++)
            pa[ks] = *(const bf16x8*)(psw + c * 128 + ((g * 16 + ks * 64) ^ ((c & 7) << 4)));
#pragma unroll
        for (int nd = 0; nd < 4; nd++)
#pragma unroll
            for (int ks = 0; ks < 2; ks++)
                oacc[nd] = __builtin_amdgcn_mfma_f32_16x16x32_bf16(pa[ks], vb[nd][ks], oacc[nd], 0, 0, 0);
    }

#pragma unroll
    for (int r = 0; r < 4; r++) {
        float inv = 1.0f / l_s[r];
        size_t rowb = (size_t)((b << 8) + qt * 64 + wid * 16 + g * 4 + r) * 512 + h * 64 + c;
#pragma unroll
        for (int nd = 0; nd < 4; nd++)
            T[rowb + nd * 16] = (__bf16)(oacc[nd][r] * inv);
    }
}

// ---------------------------------------------------------------- fused residual + LayerNorm (bf16 trunk)
// u = Xb + Ob; Xb = bf16(LN(u)). Thread t owns cols 2t, 2t+1.
__global__ __launch_bounds__(256) void k_ln3(const __bf16* __restrict__ Ob,
                                             __bf16* __restrict__ Xb,
                                             const float* __restrict__ g,
                                             const float* __restrict__ bb) {
    __shared__ float red[4];
    int row = blockIdx.x, t = threadIdx.x;
    size_t base = (size_t)row * D_;
    uint ov = *(const uint*)&Ob[base + 2 * t];
    uint xv = *(const uint*)&Xb[base + 2 * t];
    float v0 = bf_val((unsigned short)xv) + bf_val((unsigned short)ov);
    float v1 = bf_val((unsigned short)(xv >> 16)) + bf_val((unsigned short)(ov >> 16));
    float s = wave_sum(v0 + v1);
    if ((t & 63) == 0) red[t >> 6] = s;
    __syncthreads();
    float mean = (red[0] + red[1] + red[2] + red[3]) * (1.0f / D_);
    float d0 = v0 - mean, d1 = v1 - mean;
    float s2 = wave_sum(d0 * d0 + d1 * d1);
    __syncthreads();
    if ((t & 63) == 0) red[t >> 6] = s2;
    __syncthreads();
    float var = (red[0] + red[1] + red[2] + red[3]) * (1.0f / D_);
    float rr = rsqrtf(var + EPS);
    float2 gv = *(const float2*)&g[2 * t];
    float2 bv = *(const float2*)&bb[2 * t];
    float o0 = d0 * rr * gv.x + bv.x;
    float o1 = d1 * rr * gv.y + bv.y;
    uint pk = (uint)bf_bits(o0) | ((uint)bf_bits(o1) << 16);
    *(uint*)&Xb[base + 2 * t] = pk;
}

// ---------------------------------------------------------------- MLP head on CLS (bf16 trunk in)
__global__ __launch_bounds__(256) void k_head(const __bf16* __restrict__ Xb,
                                              const float* __restrict__ W1,
                                              const float* __restrict__ b1,
                                              const float* __restrict__ W2,
                                              const float* __restrict__ b2,
                                              float* __restrict__ out) {
    __shared__ float cls[D_];
    __shared__ float red[4];
    int b = blockIdx.x, t = threadIdx.x;
    size_t base = (size_t)(b << 8) * D_;
    cls[t]       = (float)Xb[base + t];
    cls[t + 256] = (float)Xb[base + t + 256];
    __syncthreads();
    float acc = 0.0f;
    for (int d = 0; d < D_; d++) acc = fmaf(cls[d], W1[(size_t)d * HID_ + t], acc);
    acc += b1[t];
    float hsum = wave_sum(gelu_exact(acc) * W2[t]);
    if ((t & 63) == 0) red[t >> 6] = hsum;
    __syncthreads();
    if (t == 0) out[b] = red[0] + red[1] + red[2] + red[3] + b2[0];
}

// ---------------------------------------------------------------- launch
extern "C" void kernel_launch(void* const* d_in, const int* in_sizes, int n_in,
                              void* d_out, int out_size, void* d_ws, size_t ws_size,
                              hipStream_t stream) {
    const float* atom = (const float*)d_in[0];
    const float* eb   = (const float*)d_in[1];
    const void*  mraw = d_in[2];
    const float* cls  = (const float*)d_in[3];
    const float* Wq = (const float*)d_in[4];  const float* bq = (const float*)d_in[5];
    const float* Wk = (const float*)d_in[6];  const float* bk = (const float*)d_in[7];
    const float* Wv = (const float*)d_in[8];  const float* bv = (const float*)d_in[9];
    const float* Wo = (const float*)d_in[10]; const float* bo = (const float*)d_in[11];
    const float* g1 = (const float*)d_in[12]; const float* be1 = (const float*)d_in[13];
    const float* W1 = (const float*)d_in[14]; const float* b1 = (const float*)d_in[15];
    const float* W2 = (const float*)d_in[16]; const float* b2 = (const float*)d_in[17];
    const float* g2 = (const float*)d_in[18]; const float* be2 = (const float*)d_in[19];
    const float* hW1 = (const float*)d_in[20]; const float* hb1 = (const float*)d_in[21];
    const float* hW2 = (const float*)d_in[22]; const float* hb2 = (const float*)d_in[23];
    float* out = (float*)d_out;

    // ---- workspace layout ----
    char* p = (char*)d_ws;
    __bf16* Xb    = (__bf16*)p;                p += (size_t)N_ * D_ * 2;        // bf16 residual trunk
    __bf16* Vt    = (__bf16*)p;                p += (size_t)N_ * D_ * 2;        // V^T (QKV->attn)
    __bf16* Ob    = (__bf16*)p;                p += (size_t)N_ * D_ * 2;        // GEMM bf16 out (O/FFN2 -> ln3)
    char*   R     = p;                         p += (size_t)N_ * FF_ * 2;
    __bf16* QKVb  = (__bf16*)R;                                                 // [N][1536]
    __bf16* Tb    = (__bf16*)(R + (size_t)N_ * 1536 * 2);                       // [N][512]
    __bf16* Hb    = (__bf16*)R;                                                 // [N][2048]
    uint8_t* ebt  = (uint8_t*)p;               p += (size_t)B_ * H_ * SP * SP;  // fragment-layout fp8
    __bf16* Wqkvt = (__bf16*)p;                p += (size_t)L_ * 1536 * 512 * 2;
    __bf16* Wot   = (__bf16*)p;                p += (size_t)L_ * 512 * 512 * 2;
    __bf16* W1t   = (__bf16*)p;                p += (size_t)L_ * 2048 * 512 * 2;
    __bf16* W2t   = (__bf16*)p;                p += (size_t)L_ * 512 * 2048 * 2;
    float*  bqkv  = (float*)p;                 p += (size_t)L_ * 1536 * 4;
    float*  mskadd= (float*)p;                 p += (size_t)B_ * SP * 4;
    int* flag = (int*)p;

    // ---- prep ----
    hipMemsetAsync(flag, 0, 4, stream);
    k_mask_detect<<<16, 256, 0, stream>>>((const unsigned int*)mraw, (B_ * S_) / 4, flag);
    k_mask_prep<<<(B_ * SP) / 256, 256, 0, stream>>>(mraw, flag, mskadd);
    k_bcat<<<(L_ * 1536) / 256, 256, 0, stream>>>(bq, bk, bv, bqkv);
    k_wt<<<dim3(8, 8, L_),  256, 0, stream>>>(Wq, Wqkvt, 512, 512, 0,    262144, 786432);
    k_wt<<<dim3(8, 8, L_),  256, 0, stream>>>(Wk, Wqkvt, 512, 512, 512,  262144, 786432);
    k_wt<<<dim3(8, 8, L_),  256, 0, stream>>>(Wv, Wqkvt, 512, 512, 1024, 262144, 786432);
    k_wt<<<dim3(8, 8, L_),  256, 0, stream>>>(Wo, Wot,   512, 512, 0,    262144, 262144);
    k_wt<<<dim3(32, 8, L_), 256, 0, stream>>>(W1, W1t,   512, 2048, 0,   1048576, 1048576);
    k_wt<<<dim3(8, 32, L_), 256, 0, stream>>>(W2, W2t,   2048, 512, 0,   1048576, 1048576);
    k_ebt5<<<B_ * 16, 256, 0, stream>>>(eb, ebt);
    k_build_x<<<(N_ * D_) / 256, 256, 0, stream>>>(atom, cls, Xb);

    for (int l = 0; l < L_; l++) {
        k_gemm2<0><<<1536, 256, 0, stream>>>(Xb, Wqkvt + (size_t)l * 786432, bqkv + l * 1536,
                                             QKVb, Vt, 512, 1536, 12);
        k_attn<<<B_ * H_ * 4, 256, 0, stream>>>(QKVb, ebt, mskadd, Vt, Tb);
        k_gemm2<0><<<512, 256, 0, stream>>>(Tb, Wot + (size_t)l * 262144, bo + l * 512,
                                            Ob, nullptr, 512, 512, 4);
        k_ln3<<<N_, 256, 0, stream>>>(Ob, Xb, g1 + l * D_, be1 + l * D_);
        k_gemm2<1><<<2048, 256, 0, stream>>>(Xb, W1t + (size_t)l * 1048576, b1 + l * FF_,
                                             Hb, nullptr, 512, 2048, 16);
        k_gemm2<0><<<512, 256, 0, stream>>>(Hb, W2t + (size_t)l * 1048576, b2 + l * D_,
                                            Ob, nullptr, 2048, 512, 4);
        k_ln3<<<N_, 256, 0, stream>>>(Ob, Xb, g2 + l * D_, be2 + l * D_);
    }
    k_head<<<B_, 256, 0, stream>>>(Xb, hW1, hb1, hW2, hb2, out);
}

// Round 11
// 3921.213 us; speedup vs baseline: 1.8375x; 1.8375x over previous
//
#include <hip/hip_runtime.h>
#include <math.h>
#include <stdint.h>

#define B_   64
#define S_   255
#define SP   256
#define D_   512
#define H_   8
#define L_   6
#define FF_  2048
#define HID_ 256
#define N_   (B_*SP)       // 16384 rows
#define EPS  1e-5f

using bf16x8 = __bf16 __attribute__((ext_vector_type(8)));
using f32x4  = float __attribute__((ext_vector_type(4)));
using u16x4  = unsigned short __attribute__((ext_vector_type(4)));

// ---------------------------------------------------------------- utilities
__device__ inline float wave_sum(float v) {
#pragma unroll
    for (int off = 32; off; off >>= 1) v += __shfl_xor(v, off);
    return v;
}

// fast exact-erf gelu: A&S 7.1.26 polynomial, |erf err| <= 1.5e-7
__device__ inline float gelu_exact(float x) {
    float z  = fabsf(x) * 0.70710678118654752f;
    float tt = __builtin_amdgcn_rcpf(fmaf(0.3275911f, z, 1.0f));
    float poly = tt * (0.254829592f + tt * (-0.284496736f + tt * (1.421413741f +
                 tt * (-1.453152027f + tt * 1.061405429f))));
    float er = 1.0f - poly * __expf(-z * z);
    er = copysignf(er, x);
    return 0.5f * x * (1.0f + er);
}

__device__ inline unsigned short bf_bits(float x) {
    __bf16 h = (__bf16)x;
    return *(unsigned short*)&h;
}

__device__ inline float bf_val(unsigned short u) {
    __bf16 h = *(__bf16*)&u;
    return (float)h;
}

// fp8 e4m3fn encode (RNE) / decode
__device__ inline uint8_t enc_e4m3(float f) {
    uint32_t u = __float_as_uint(f);
    uint32_t s = (u >> 24) & 0x80u;
    float a = fabsf(f);
    if (a < 0.015625f) {
        int m = (int)rintf(a * 512.0f);
        if (m >= 8) return (uint8_t)(s | 0x08);
        return (uint8_t)(s | (uint32_t)m);
    }
    if (a > 448.0f) return (uint8_t)(s | 0x7E);
    uint32_t b = __float_as_uint(a);
    uint32_t expf_ = b >> 23;
    uint32_t mant = b & 0x7FFFFF;
    uint32_t keep = mant >> 20;
    uint32_t rest = mant & 0xFFFFF;
    if (rest > 0x80000u || (rest == 0x80000u && (keep & 1))) keep++;
    if (keep == 8) { keep = 0; expf_++; }
    int e8 = (int)expf_ - 120;
    if (e8 >= 16) return (uint8_t)(s | 0x7E);
    return (uint8_t)(s | ((uint32_t)e8 << 3) | keep);
}

__device__ inline float dec_e4m3(uint32_t b) {
    uint32_t mag = b & 0x7Fu;
    float fm = __uint_as_float((mag << 20) + (120u << 23));
    if ((mag >> 3) == 0) fm = fm * 2.0f - 0.015625f;
    return (b & 0x80u) ? -fm : fm;
}

// async global->LDS 16B (m97 recipe)
#define GLOAD16(gsrc, ldst) \
    __builtin_amdgcn_global_load_lds((const __attribute__((address_space(1))) unsigned int*)(gsrc), \
                                     (__attribute__((address_space(3))) unsigned int*)(ldst), 16, 0, 0)

// ---------------------------------------------------------------- build Xb = [cls; atom] (bf16 trunk)
__global__ void k_build_x(const float* __restrict__ atom, const float* __restrict__ cls,
                          __bf16* __restrict__ Xb) {
    int idx = blockIdx.x * 256 + threadIdx.x;
    int col = idx & (D_ - 1);
    int row = idx >> 9;
    int sr  = row & (SP - 1);
    int b   = row >> 8;
    float v = (sr == 0) ? cls[col] : atom[((size_t)(b * S_) + (sr - 1)) * D_ + col];
    Xb[idx] = (__bf16)v;
}

// ---------------------------------------------------------------- mask layout detection
__global__ void k_mask_detect(const unsigned int* __restrict__ mw, int nw, int* flag) {
    int i = blockIdx.x * 256 + threadIdx.x;
    if (i < nw && mw[i] > 1u) atomicOr(flag, 1);
}

__global__ void k_mask_prep(const void* __restrict__ mraw, const int* __restrict__ flag,
                            float* __restrict__ mskadd) {
    int i = blockIdx.x * 256 + threadIdx.x;
    int b = i >> 8, j = i & 255;
    float v = 0.0f;
    if (j > 0) {
        int src = b * S_ + (j - 1);
        bool m = (*flag) ? (((const unsigned char*)mraw)[src] != 0)
                         : (((const int*)mraw)[src] != 0);
        if (m) v = -1e30f;
    }
    mskadd[i] = v;
}

// ---------------------------------------------------------------- weight transpose+cast
__global__ __launch_bounds__(256) void k_wt(const float* __restrict__ W, __bf16* __restrict__ Wt,
                                            int K, int Mw, int mout_off,
                                            size_t in_lstride, size_t out_lstride) {
    __shared__ float T[64][65];
    int l = blockIdx.z;
    int m0 = blockIdx.x * 64, k0 = blockIdx.y * 64;
    const float* Wl = W + (size_t)l * in_lstride;
    __bf16* Wtl = Wt + (size_t)l * out_lstride;
    int tid = threadIdx.x;
    int cc = tid & 63, rr = tid >> 6;
#pragma unroll
    for (int p = 0; p < 16; p++) {
        int kk = rr + p * 4;
        T[kk][cc] = Wl[(size_t)(k0 + kk) * Mw + m0 + cc];
    }
    __syncthreads();
#pragma unroll
    for (int p = 0; p < 16; p++) {
        int mm = rr + p * 4;
        Wtl[(size_t)(mout_off + m0 + mm) * K + k0 + cc] = (__bf16)T[cc][mm];
    }
}

// ---------------------------------------------------------------- qkv bias concat
__global__ void k_bcat(const float* __restrict__ bq, const float* __restrict__ bk,
                       const float* __restrict__ bv, float* __restrict__ bqkv) {
    int i = blockIdx.x * 256 + threadIdx.x;
    int l = i / 1536, c = i % 1536;
    float v;
    if (c < 512)       v = bq[l * 512 + c];
    else if (c < 1024) v = bk[l * 512 + c - 512];
    else               v = bv[l * 512 + c - 1024];
    bqkv[i] = v;
}

// ---------------------------------------------------------------- bias repack, coalesced both sides
__global__ __launch_bounds__(256) void k_ebt5(const float* __restrict__ eb, uint8_t* __restrict__ ebt) {
    __shared__ uint8_t Ls[8 * 16 * 260];           // [h][qi][260], odd-dword qi stride
    int blk = blockIdx.x;                          // 64*16
    int b = blk >> 4, wm = blk & 15;
    int w = wm >> 2, mq = wm & 3;
    int qbase = w * 64 + mq * 16;
    int t = threadIdx.x;
    for (int qi = 0; qi < 16; qi++) {
        int q = qbase + qi;
        if (q > 0) {
            const float4* src = (const float4*)(eb + ((size_t)(b * 255) + (q - 1)) * 2040);
#pragma unroll
            for (int p = 0; p < 2; p++) {
                int idx4 = t + p * 256;
                if (idx4 < 510) {
                    float4 v = src[idx4];
                    int k  = idx4 >> 1;
                    int h0 = (idx4 & 1) * 4;
                    Ls[((h0 + 0) * 16 + qi) * 260 + k] = enc_e4m3(v.x);
                    Ls[((h0 + 1) * 16 + qi) * 260 + k] = enc_e4m3(v.y);
                    Ls[((h0 + 2) * 16 + qi) * 260 + k] = enc_e4m3(v.z);
                    Ls[((h0 + 3) * 16 + qi) * 260 + k] = enc_e4m3(v.w);
                }
            }
        }
    }
    __syncthreads();
    int cc = t >> 4, qi = t & 15;
    int q = qbase + qi;
    uint32_t* outp = (uint32_t*)ebt;
#pragma unroll
    for (int h = 0; h < 8; h++) {
#pragma unroll
        for (int tl = 0; tl < 4; tl++) {
            uint32_t d = 0;
            if (q > 0) {
#pragma unroll
                for (int nk = 0; nk < 4; nk++) {
                    int k = tl * 64 + nk * 16 + cc;
                    if (k > 0) d |= (uint32_t)Ls[(h * 16 + qi) * 260 + (k - 1)] << (nk * 8);
                }
            }
            size_t x = ((((size_t)(b * 8 + h) * 4 + tl) * 4 + w) * 4 + mq) * 256 + t;
            outp[x] = d;
        }
    }
}

// ---------------------------------------------------------------- 128x128 single-buffer MFMA GEMM
// m97 recipe at BK=64: 32 KB LDS; __launch_bounds__(256,4) -- NOT 5: round-10 post-mortem
// showed (256,5) clamps VGPR to 48 and spills the accumulator to scratch (886 MB writes).
// T1 XCD swizzle; T2 both-sides XOR involution; T5 setprio.
template<int GELU>
__global__ __launch_bounds__(256, 4) void k_gemm2(const __bf16* __restrict__ Ag,
                                                  const __bf16* __restrict__ Bg,
                                                  const float* __restrict__ bias,
                                                  __bf16* __restrict__ Cb,
                                                  __bf16* __restrict__ vtout,
                                                  int K, int M, int gx) {
    __shared__ __align__(16) __bf16 AS[128 * 64];
    __shared__ __align__(16) __bf16 BS[128 * 64];
    const int tid = threadIdx.x;
    const int w = tid >> 6, lane = tid & 63;
    const int wr = w >> 1, wc = w & 1;
    const int lrow = lane & 15, lg = lane >> 4;
    const int nwg = gridDim.x, bid = blockIdx.x;
    const int swz = (bid & 7) * (nwg >> 3) + (bid >> 3);   // T1 (nwg % 8 == 0)
    const int by = swz / gx, bx = swz - by * gx;
    const int rowbase = by * 128, colbase = bx * 128;
    const int nkt = K >> 6;

    f32x4 acc[4][4];
#pragma unroll
    for (int m = 0; m < 4; m++)
#pragma unroll
        for (int n = 0; n < 4; n++) acc[m][n] = f32x4{0.f, 0.f, 0.f, 0.f};

    for (int kt = 0; kt < nkt; ++kt) {
        if (kt) __builtin_amdgcn_s_barrier();      // prior tile's ds_reads done
        __builtin_amdgcn_sched_barrier(0);
#pragma unroll
        for (int p = 0; p < 4; p++) {
            int s = tid + p * 256;                 // 1024 slots of 16B
            int row = s >> 3, sg = s & 7;
            GLOAD16(Ag + (size_t)(rowbase + row) * K + kt * 64 + ((sg ^ (row & 7)) << 3), &AS[s * 8]);
            GLOAD16(Bg + (size_t)(colbase + row) * K + kt * 64 + ((sg ^ (row & 7)) << 3), &BS[s * 8]);
        }
        asm volatile("s_waitcnt vmcnt(0)" ::: "memory");
        __builtin_amdgcn_s_barrier();

        bf16x8 aF[4][2], bF[4][2];
#pragma unroll
        for (int m = 0; m < 4; m++) {
            int arow = wr * 64 + m * 16 + lrow;
#pragma unroll
            for (int ks = 0; ks < 2; ks++) {
                int sl = (lg + ks * 4) ^ (arow & 7);
                aF[m][ks] = *(const bf16x8*)&AS[arow * 64 + sl * 8];
            }
        }
#pragma unroll
        for (int n = 0; n < 4; n++) {
            int brow = wc * 64 + n * 16 + lrow;
#pragma unroll
            for (int ks = 0; ks < 2; ks++) {
                int sl = (lg + ks * 4) ^ (brow & 7);
                bF[n][ks] = *(const bf16x8*)&BS[brow * 64 + sl * 8];
            }
        }
        asm volatile("s_waitcnt lgkmcnt(0)" ::: "memory");
        __builtin_amdgcn_sched_barrier(0);         // rule #18
        __builtin_amdgcn_s_setprio(1);
#pragma unroll
        for (int m = 0; m < 4; m++)
#pragma unroll
            for (int n = 0; n < 4; n++)
#pragma unroll
                for (int ks = 0; ks < 2; ks++)
                    acc[m][n] = __builtin_amdgcn_mfma_f32_16x16x32_bf16(aF[m][ks], bF[n][ks],
                                                                        acc[m][n], 0, 0, 0);
        __builtin_amdgcn_s_setprio(0);
    }

    // ---- epilogue (bf16 out; V^T split for QKV) ----
    const bool dovt = (vtout != nullptr) && (colbase >= 1024);   // block-uniform
#pragma unroll
    for (int m = 0; m < 4; m++) {
        int row = rowbase + wr * 64 + m * 16 + lg * 4;
#pragma unroll
        for (int n = 0; n < 4; n++) {
            int col = colbase + wc * 64 + n * 16 + lrow;
            float bv = bias ? bias[col] : 0.0f;
            float v[4];
#pragma unroll
            for (int r = 0; r < 4; r++) {
                float x = acc[m][n][r] + bv;
                if (GELU) x = gelu_exact(x);
                v[r] = x;
            }
            if (dovt) {
                int hcol = col - 1024;
                int hh = hcol >> 6, d = hcol & 63;
                int bb = row >> 8, s0 = row & 255;
                u16x4 pk = { bf_bits(v[0]), bf_bits(v[1]), bf_bits(v[2]), bf_bits(v[3]) };
                *(u16x4*)&vtout[((size_t)((bb * 8 + hh) * 64 + d)) * 256 + s0] = pk;
            } else {
#pragma unroll
                for (int r = 0; r < 4; r++)
                    Cb[(size_t)(row + r) * M + col] = (__bf16)v[r];
            }
        }
    }
}

// ---------------------------------------------------------------- MFMA fused attention
// grid: 2048 blocks, XCD-swizzled. Monotone key mask -> block-uniform skip of fully-masked tiles.
__global__ __launch_bounds__(256) void k_attn(const __bf16* __restrict__ QKV,
                                              const uint8_t* __restrict__ ebt,
                                              const float* __restrict__ mskadd,
                                              const __bf16* __restrict__ Vt,
                                              __bf16* __restrict__ T) {
    __shared__ __align__(16) char Ks[8192];
    __shared__ __align__(16) char Vs[8192];
    __shared__ __align__(16) char Ps[4][2048];
    __shared__ float Ma[256];
    const int bid = blockIdx.x;
    const int swzb = (bid & 7) * 256 + (bid >> 3);     // T1, nwg = 2048
    const int bh = swzb >> 2, qt = swzb & 3;
    const int b = bh >> 3, h = bh & 7;
    const int tid = threadIdx.x, wid = tid >> 6, lane = tid & 63;
    const int g = lane >> 4, c = lane & 15;

    Ma[tid] = mskadd[(b << 8) + tid];

    bf16x8 qf[2];
    {
        const __bf16* qrow = QKV + (size_t)((b << 8) + qt * 64 + wid * 16 + c) * 1536 + h * 64;
        qf[0] = *(const bf16x8*)(qrow + g * 8);
        qf[1] = *(const bf16x8*)(qrow + 32 + g * 8);
    }

    f32x4 oacc[4];
    float m_s[4], l_s[4];
#pragma unroll
    for (int r = 0; r < 4; r++) { m_s[r] = -1e30f; l_s[r] = 0.0f; }
#pragma unroll
    for (int nd = 0; nd < 4; nd++) oacc[nd] = f32x4{0.f, 0.f, 0.f, 0.f};

    for (int t = 0; t < 4; t++) {
        const int t0 = t * 64;
        __syncthreads();
        if (t0 > 0 && Ma[t0] < -0.5f) continue;    // monotone mask: whole tile masked
#pragma unroll
        for (int p = 0; p < 2; p++) {
            int idx = tid + p * 256;
            int row = idx >> 3, c8 = idx & 7;
            int lds = row * 128 + ((c8 * 16) ^ ((row & 7) << 4));
            *(uint4*)(Ks + lds) = *(const uint4*)&QKV[(size_t)((b << 8) + t0 + row) * 1536 + 512 + h * 64 + c8 * 8];
            *(uint4*)(Vs + lds) = *(const uint4*)&Vt[((size_t)bh * 64 + row) * 256 + t0 + c8 * 8];
        }
        __syncthreads();

        bf16x8 kf[4][2], vb[4][2];
#pragma unroll
        for (int n = 0; n < 4; n++) {
            int row = n * 16 + c;
#pragma unroll
            for (int ks = 0; ks < 2; ks++) {
                int col = (g * 16 + ks * 64) ^ ((row & 7) << 4);
                kf[n][ks] = *(const bf16x8*)(Ks + row * 128 + col);
                vb[n][ks] = *(const bf16x8*)(Vs + row * 128 + col);
            }
        }

        f32x4 sa[4];
#pragma unroll
        for (int nk = 0; nk < 4; nk++) sa[nk] = f32x4{0.f, 0.f, 0.f, 0.f};
#pragma unroll
        for (int ks = 0; ks < 2; ks++)
#pragma unroll
            for (int nk = 0; nk < 4; nk++)
                sa[nk] = __builtin_amdgcn_mfma_f32_16x16x32_bf16(qf[ks], kf[nk][ks], sa[nk], 0, 0, 0);

        uint4 b4 = *(const uint4*)(ebt + ((((size_t)bh * 4 + t) * 4 + qt) * 4 + wid) * 1024 + c * 64 + g * 16);
        uint32_t bw[4] = { b4.x, b4.y, b4.z, b4.w };
        float s[4][4];                             // [nk][r]
#pragma unroll
        for (int nk = 0; nk < 4; nk++) {
            float ma = Ma[t0 + nk * 16 + c];
#pragma unroll
            for (int r = 0; r < 4; r++)
                s[nk][r] = sa[nk][r] * 0.125f + dec_e4m3((bw[r] >> (nk * 8)) & 0xFF) + ma;
        }

        float corr[4];
#pragma unroll
        for (int r = 0; r < 4; r++) {
            float tm = fmaxf(fmaxf(s[0][r], s[1][r]), fmaxf(s[2][r], s[3][r]));
#pragma unroll
            for (int off = 1; off < 16; off <<= 1)
                tm = fmaxf(tm, __shfl_xor(tm, off));
            float mnew = fmaxf(m_s[r], tm);
            corr[r] = __expf(m_s[r] - mnew);
            m_s[r] = mnew;
            float psum = 0.0f;
#pragma unroll
            for (int nk = 0; nk < 4; nk++) {
                s[nk][r] = __expf(s[nk][r] - mnew);
                psum += s[nk][r];
            }
#pragma unroll
            for (int off = 1; off < 16; off <<= 1)
                psum += __shfl_xor(psum, off);
            l_s[r] = l_s[r] * corr[r] + psum;
        }
#pragma unroll
        for (int nd = 0; nd < 4; nd++)
#pragma unroll
            for (int r = 0; r < 4; r++)
                oacc[nd][r] *= corr[r];

        char* psw = Ps[wid];
#pragma unroll
        for (int r = 0; r < 4; r++) {
            int qs = g * 4 + r;
#pragma unroll
            for (int nk = 0; nk < 4; nk++)
                *(__bf16*)(psw + qs * 128 + ((nk * 32 + c * 2) ^ ((qs & 7) << 4))) = (__bf16)s[nk][r];
        }
        bf16x8 pa[2];
#pragma unroll
        for (int ks = 0; ks < 2; ks++)
            pa[ks] = *(const bf16x8*)(psw + c * 128 + ((g * 16 + ks * 64) ^ ((c & 7) << 4)));
#pragma unroll
        for (int nd = 0; nd < 4; nd++)
#pragma unroll
            for (int ks = 0; ks < 2; ks++)
                oacc[nd] = __builtin_amdgcn_mfma_f32_16x16x32_bf16(pa[ks], vb[nd][ks], oacc[nd], 0, 0, 0);
    }

#pragma unroll
    for (int r = 0; r < 4; r++) {
        float inv = 1.0f / l_s[r];
        size_t rowb = (size_t)((b << 8) + qt * 64 + wid * 16 + g * 4 + r) * 512 + h * 64 + c;
#pragma unroll
        for (int nd = 0; nd < 4; nd++)
            T[rowb + nd * 16] = (__bf16)(oacc[nd][r] * inv);
    }
}

// ---------------------------------------------------------------- fused residual + LayerNorm (bf16 trunk)
// u = Xb + Ob; Xb = bf16(LN(u)). Thread t owns cols 2t, 2t+1.
__global__ __launch_bounds__(256) void k_ln3(const __bf16* __restrict__ Ob,
                                             __bf16* __restrict__ Xb,
                                             const float* __restrict__ g,
                                             const float* __restrict__ bb) {
    __shared__ float red[4];
    int row = blockIdx.x, t = threadIdx.x;
    size_t base = (size_t)row * D_;
    uint ov = *(const uint*)&Ob[base + 2 * t];
    uint xv = *(const uint*)&Xb[base + 2 * t];
    float v0 = bf_val((unsigned short)xv) + bf_val((unsigned short)ov);
    float v1 = bf_val((unsigned short)(xv >> 16)) + bf_val((unsigned short)(ov >> 16));
    float s = wave_sum(v0 + v1);
    if ((t & 63) == 0) red[t >> 6] = s;
    __syncthreads();
    float mean = (red[0] + red[1] + red[2] + red[3]) * (1.0f / D_);
    float d0 = v0 - mean, d1 = v1 - mean;
    float s2 = wave_sum(d0 * d0 + d1 * d1);
    __syncthreads();
    if ((t & 63) == 0) red[t >> 6] = s2;
    __syncthreads();
    float var = (red[0] + red[1] + red[2] + red[3]) * (1.0f / D_);
    float rr = rsqrtf(var + EPS);
    float2 gv = *(const float2*)&g[2 * t];
    float2 bv = *(const float2*)&bb[2 * t];
    float o0 = d0 * rr * gv.x + bv.x;
    float o1 = d1 * rr * gv.y + bv.y;
    uint pk = (uint)bf_bits(o0) | ((uint)bf_bits(o1) << 16);
    *(uint*)&Xb[base + 2 * t] = pk;
}

// ---------------------------------------------------------------- MLP head on CLS (bf16 trunk in)
__global__ __launch_bounds__(256) void k_head(const __bf16* __restrict__ Xb,
                                              const float* __restrict__ W1,
                                              const float* __restrict__ b1,
                                              const float* __restrict__ W2,
                                              const float* __restrict__ b2,
                                              float* __restrict__ out) {
    __shared__ float cls[D_];
    __shared__ float red[4];
    int b = blockIdx.x, t = threadIdx.x;
    size_t base = (size_t)(b << 8) * D_;
    cls[t]       = (float)Xb[base + t];
    cls[t + 256] = (float)Xb[base + t + 256];
    __syncthreads();
    float acc = 0.0f;
    for (int d = 0; d < D_; d++) acc = fmaf(cls[d], W1[(size_t)d * HID_ + t], acc);
    acc += b1[t];
    float hsum = wave_sum(gelu_exact(acc) * W2[t]);
    if ((t & 63) == 0) red[t >> 6] = hsum;
    __syncthreads();
    if (t == 0) out[b] = red[0] + red[1] + red[2] + red[3] + b2[0];
}

// ---------------------------------------------------------------- launch
extern "C" void kernel_launch(void* const* d_in, const int* in_sizes, int n_in,
                              void* d_out, int out_size, void* d_ws, size_t ws_size,
                              hipStream_t stream) {
    const float* atom = (const float*)d_in[0];
    const float* eb   = (const float*)d_in[1];
    const void*  mraw = d_in[2];
    const float* cls  = (const float*)d_in[3];
    const float* Wq = (const float*)d_in[4];  const float* bq = (const float*)d_in[5];
    const float* Wk = (const float*)d_in[6];  const float* bk = (const float*)d_in[7];
    const float* Wv = (const float*)d_in[8];  const float* bv = (const float*)d_in[9];
    const float* Wo = (const float*)d_in[10]; const float* bo = (const float*)d_in[11];
    const float* g1 = (const float*)d_in[12]; const float* be1 = (const float*)d_in[13];
    const float* W1 = (const float*)d_in[14]; const float* b1 = (const float*)d_in[15];
    const float* W2 = (const float*)d_in[16]; const float* b2 = (const float*)d_in[17];
    const float* g2 = (const float*)d_in[18]; const float* be2 = (const float*)d_in[19];
    const float* hW1 = (const float*)d_in[20]; const float* hb1 = (const float*)d_in[21];
    const float* hW2 = (const float*)d_in[22]; const float* hb2 = (const float*)d_in[23];
    float* out = (float*)d_out;

    // ---- workspace layout ----
    char* p = (char*)d_ws;
    __bf16* Xb    = (__bf16*)p;                p += (size_t)N_ * D_ * 2;        // bf16 residual trunk
    __bf16* Vt    = (__bf16*)p;                p += (size_t)N_ * D_ * 2;        // V^T (QKV->attn)
    __bf16* Ob    = (__bf16*)p;                p += (size_t)N_ * D_ * 2;        // GEMM bf16 out (O/FFN2 -> ln3)
    char*   R     = p;                         p += (size_t)N_ * FF_ * 2;
    __bf16* QKVb  = (__bf16*)R;                                                 // [N][1536]
    __bf16* Tb    = (__bf16*)(R + (size_t)N_ * 1536 * 2);                       // [N][512]
    __bf16* Hb    = (__bf16*)R;                                                 // [N][2048]
    uint8_t* ebt  = (uint8_t*)p;               p += (size_t)B_ * H_ * SP * SP;  // fragment-layout fp8
    __bf16* Wqkvt = (__bf16*)p;                p += (size_t)L_ * 1536 * 512 * 2;
    __bf16* Wot   = (__bf16*)p;                p += (size_t)L_ * 512 * 512 * 2;
    __bf16* W1t   = (__bf16*)p;                p += (size_t)L_ * 2048 * 512 * 2;
    __bf16* W2t   = (__bf16*)p;                p += (size_t)L_ * 512 * 2048 * 2;
    float*  bqkv  = (float*)p;                 p += (size_t)L_ * 1536 * 4;
    float*  mskadd= (float*)p;                 p += (size_t)B_ * SP * 4;
    int* flag = (int*)p;

    // ---- prep ----
    hipMemsetAsync(flag, 0, 4, stream);
    k_mask_detect<<<16, 256, 0, stream>>>((const unsigned int*)mraw, (B_ * S_) / 4, flag);
    k_mask_prep<<<(B_ * SP) / 256, 256, 0, stream>>>(mraw, flag, mskadd);
    k_bcat<<<(L_ * 1536) / 256, 256, 0, stream>>>(bq, bk, bv, bqkv);
    k_wt<<<dim3(8, 8, L_),  256, 0, stream>>>(Wq, Wqkvt, 512, 512, 0,    262144, 786432);
    k_wt<<<dim3(8, 8, L_),  256, 0, stream>>>(Wk, Wqkvt, 512, 512, 512,  262144, 786432);
    k_wt<<<dim3(8, 8, L_),  256, 0, stream>>>(Wv, Wqkvt, 512, 512, 1024, 262144, 786432);
    k_wt<<<dim3(8, 8, L_),  256, 0, stream>>>(Wo, Wot,   512, 512, 0,    262144, 262144);
    k_wt<<<dim3(32, 8, L_), 256, 0, stream>>>(W1, W1t,   512, 2048, 0,   1048576, 1048576);
    k_wt<<<dim3(8, 32, L_), 256, 0, stream>>>(W2, W2t,   2048, 512, 0,   1048576, 1048576);
    k_ebt5<<<B_ * 16, 256, 0, stream>>>(eb, ebt);
    k_build_x<<<(N_ * D_) / 256, 256, 0, stream>>>(atom, cls, Xb);

    for (int l = 0; l < L_; l++) {
        k_gemm2<0><<<1536, 256, 0, stream>>>(Xb, Wqkvt + (size_t)l * 786432, bqkv + l * 1536,
                                             QKVb, Vt, 512, 1536, 12);
        k_attn<<<B_ * H_ * 4, 256, 0, stream>>>(QKVb, ebt, mskadd, Vt, Tb);
        k_gemm2<0><<<512, 256, 0, stream>>>(Tb, Wot + (size_t)l * 262144, bo + l * 512,
                                            Ob, nullptr, 512, 512, 4);
        k_ln3<<<N_, 256, 0, stream>>>(Ob, Xb, g1 + l * D_, be1 + l * D_);
        k_gemm2<1><<<2048, 256, 0, stream>>>(Xb, W1t + (size_t)l * 1048576, b1 + l * FF_,
                                             Hb, nullptr, 512, 2048, 16);
        k_gemm2<0><<<512, 256, 0, stream>>>(Hb, W2t + (size_t)l * 1048576, b2 + l * D_,
                                            Ob, nullptr, 2048, 512, 4);
        k_ln3<<<N_, 256, 0, stream>>>(Ob, Xb, g2 + l * D_, be2 + l * D_);
    }
    k_head<<<B_, 256, 0, stream>>>(Xb, hW1, hb1, hW2, hb2, out);
}

// Round 12
// 1590.740 us; speedup vs baseline: 4.5296x; 2.4650x over previous
//
#include <hip/hip_runtime.h>
#include <math.h>
#include <stdint.h>

#define B_   64
#define S_   255
#define SP   256
#define D_   512
#define H_   8
#define L_   6
#define FF_  2048
#define HID_ 256
#define N_   (B_*SP)       // 16384 rows
#define EPS  1e-5f

using bf16x8 = __bf16 __attribute__((ext_vector_type(8)));
using f32x4  = float __attribute__((ext_vector_type(4)));
using u16x4  = unsigned short __attribute__((ext_vector_type(4)));

// ---------------------------------------------------------------- utilities
__device__ inline float wave_sum(float v) {
#pragma unroll
    for (int off = 32; off; off >>= 1) v += __shfl_xor(v, off);
    return v;
}

// fast exact-erf gelu: A&S 7.1.26 polynomial, |erf err| <= 1.5e-7
__device__ inline float gelu_exact(float x) {
    float z  = fabsf(x) * 0.70710678118654752f;
    float tt = __builtin_amdgcn_rcpf(fmaf(0.3275911f, z, 1.0f));
    float poly = tt * (0.254829592f + tt * (-0.284496736f + tt * (1.421413741f +
                 tt * (-1.453152027f + tt * 1.061405429f))));
    float er = 1.0f - poly * __expf(-z * z);
    er = copysignf(er, x);
    return 0.5f * x * (1.0f + er);
}

__device__ inline unsigned short bf_bits(float x) {
    __bf16 h = (__bf16)x;
    return *(unsigned short*)&h;
}

__device__ inline float bf_val(unsigned short u) {
    __bf16 h = *(__bf16*)&u;
    return (float)h;
}

// fp8 e4m3fn encode (RNE) / decode
__device__ inline uint8_t enc_e4m3(float f) {
    uint32_t u = __float_as_uint(f);
    uint32_t s = (u >> 24) & 0x80u;
    float a = fabsf(f);
    if (a < 0.015625f) {
        int m = (int)rintf(a * 512.0f);
        if (m >= 8) return (uint8_t)(s | 0x08);
        return (uint8_t)(s | (uint32_t)m);
    }
    if (a > 448.0f) return (uint8_t)(s | 0x7E);
    uint32_t b = __float_as_uint(a);
    uint32_t expf_ = b >> 23;
    uint32_t mant = b & 0x7FFFFF;
    uint32_t keep = mant >> 20;
    uint32_t rest = mant & 0xFFFFF;
    if (rest > 0x80000u || (rest == 0x80000u && (keep & 1))) keep++;
    if (keep == 8) { keep = 0; expf_++; }
    int e8 = (int)expf_ - 120;
    if (e8 >= 16) return (uint8_t)(s | 0x7E);
    return (uint8_t)(s | ((uint32_t)e8 << 3) | keep);
}

__device__ inline float dec_e4m3(uint32_t b) {
    uint32_t mag = b & 0x7Fu;
    float fm = __uint_as_float((mag << 20) + (120u << 23));
    if ((mag >> 3) == 0) fm = fm * 2.0f - 0.015625f;
    return (b & 0x80u) ? -fm : fm;
}

// async global->LDS 16B (m97 recipe)
#define GLOAD16(gsrc, ldst) \
    __builtin_amdgcn_global_load_lds((const __attribute__((address_space(1))) unsigned int*)(gsrc), \
                                     (__attribute__((address_space(3))) unsigned int*)(ldst), 16, 0, 0)

// ---------------------------------------------------------------- build Xb = [cls; atom] (bf16 trunk)
__global__ void k_build_x(const float* __restrict__ atom, const float* __restrict__ cls,
                          __bf16* __restrict__ Xb) {
    int idx = blockIdx.x * 256 + threadIdx.x;
    int col = idx & (D_ - 1);
    int row = idx >> 9;
    int sr  = row & (SP - 1);
    int b   = row >> 8;
    float v = (sr == 0) ? cls[col] : atom[((size_t)(b * S_) + (sr - 1)) * D_ + col];
    Xb[idx] = (__bf16)v;
}

// ---------------------------------------------------------------- mask layout detection
__global__ void k_mask_detect(const unsigned int* __restrict__ mw, int nw, int* flag) {
    int i = blockIdx.x * 256 + threadIdx.x;
    if (i < nw && mw[i] > 1u) atomicOr(flag, 1);
}

__global__ void k_mask_prep(const void* __restrict__ mraw, const int* __restrict__ flag,
                            float* __restrict__ mskadd) {
    int i = blockIdx.x * 256 + threadIdx.x;
    int b = i >> 8, j = i & 255;
    float v = 0.0f;
    if (j > 0) {
        int src = b * S_ + (j - 1);
        bool m = (*flag) ? (((const unsigned char*)mraw)[src] != 0)
                         : (((const int*)mraw)[src] != 0);
        if (m) v = -1e30f;
    }
    mskadd[i] = v;
}

// ---------------------------------------------------------------- weight transpose+cast
__global__ __launch_bounds__(256) void k_wt(const float* __restrict__ W, __bf16* __restrict__ Wt,
                                            int K, int Mw, int mout_off,
                                            size_t in_lstride, size_t out_lstride) {
    __shared__ float T[64][65];
    int l = blockIdx.z;
    int m0 = blockIdx.x * 64, k0 = blockIdx.y * 64;
    const float* Wl = W + (size_t)l * in_lstride;
    __bf16* Wtl = Wt + (size_t)l * out_lstride;
    int tid = threadIdx.x;
    int cc = tid & 63, rr = tid >> 6;
#pragma unroll
    for (int p = 0; p < 16; p++) {
        int kk = rr + p * 4;
        T[kk][cc] = Wl[(size_t)(k0 + kk) * Mw + m0 + cc];
    }
    __syncthreads();
#pragma unroll
    for (int p = 0; p < 16; p++) {
        int mm = rr + p * 4;
        Wtl[(size_t)(mout_off + m0 + mm) * K + k0 + cc] = (__bf16)T[cc][mm];
    }
}

// ---------------------------------------------------------------- qkv bias concat
__global__ void k_bcat(const float* __restrict__ bq, const float* __restrict__ bk,
                       const float* __restrict__ bv, float* __restrict__ bqkv) {
    int i = blockIdx.x * 256 + threadIdx.x;
    int l = i / 1536, c = i % 1536;
    float v;
    if (c < 512)       v = bq[l * 512 + c];
    else if (c < 1024) v = bk[l * 512 + c - 512];
    else               v = bv[l * 512 + c - 1024];
    bqkv[i] = v;
}

// ---------------------------------------------------------------- bias repack, coalesced both sides
__global__ __launch_bounds__(256) void k_ebt5(const float* __restrict__ eb, uint8_t* __restrict__ ebt) {
    __shared__ uint8_t Ls[8 * 16 * 260];           // [h][qi][260], odd-dword qi stride
    int blk = blockIdx.x;                          // 64*16
    int b = blk >> 4, wm = blk & 15;
    int w = wm >> 2, mq = wm & 3;
    int qbase = w * 64 + mq * 16;
    int t = threadIdx.x;
    for (int qi = 0; qi < 16; qi++) {
        int q = qbase + qi;
        if (q > 0) {
            const float4* src = (const float4*)(eb + ((size_t)(b * 255) + (q - 1)) * 2040);
#pragma unroll
            for (int p = 0; p < 2; p++) {
                int idx4 = t + p * 256;
                if (idx4 < 510) {
                    float4 v = src[idx4];
                    int k  = idx4 >> 1;
                    int h0 = (idx4 & 1) * 4;
                    Ls[((h0 + 0) * 16 + qi) * 260 + k] = enc_e4m3(v.x);
                    Ls[((h0 + 1) * 16 + qi) * 260 + k] = enc_e4m3(v.y);
                    Ls[((h0 + 2) * 16 + qi) * 260 + k] = enc_e4m3(v.z);
                    Ls[((h0 + 3) * 16 + qi) * 260 + k] = enc_e4m3(v.w);
                }
            }
        }
    }
    __syncthreads();
    int cc = t >> 4, qi = t & 15;
    int q = qbase + qi;
    uint32_t* outp = (uint32_t*)ebt;
#pragma unroll
    for (int h = 0; h < 8; h++) {
#pragma unroll
        for (int tl = 0; tl < 4; tl++) {
            uint32_t d = 0;
            if (q > 0) {
#pragma unroll
                for (int nk = 0; nk < 4; nk++) {
                    int k = tl * 64 + nk * 16 + cc;
                    if (k > 0) d |= (uint32_t)Ls[(h * 16 + qi) * 260 + (k - 1)] << (nk * 8);
                }
            }
            size_t x = ((((size_t)(b * 8 + h) * 4 + tl) * 4 + w) * 4 + mq) * 256 + t;
            outp[x] = d;
        }
    }
}

// ---------------------------------------------------------------- 128x128 single-buffer MFMA GEMM
// m97 recipe at BK=64: 32 KB LDS; __launch_bounds__(256,2) -- the allocator caps arch-VGPRs
// at ~256/min_waves on this toolchain (rounds 10/11: min_waves=5 -> 48 VGPR, =4 -> 64 VGPR,
// both spill acc to scratch at 350-890 MB writes). min_waves=2 -> 88 VGPR, no spill; with
// 32 KB LDS the occupancy limiter is then VGPRs (~4 blocks/CU).
// T1 XCD swizzle; T2 both-sides XOR involution; T5 setprio.
template<int GELU>
__global__ __launch_bounds__(256, 2) void k_gemm2(const __bf16* __restrict__ Ag,
                                                  const __bf16* __restrict__ Bg,
                                                  const float* __restrict__ bias,
                                                  __bf16* __restrict__ Cb,
                                                  __bf16* __restrict__ vtout,
                                                  int K, int M, int gx) {
    __shared__ __align__(16) __bf16 AS[128 * 64];
    __shared__ __align__(16) __bf16 BS[128 * 64];
    const int tid = threadIdx.x;
    const int w = tid >> 6, lane = tid & 63;
    const int wr = w >> 1, wc = w & 1;
    const int lrow = lane & 15, lg = lane >> 4;
    const int nwg = gridDim.x, bid = blockIdx.x;
    const int swz = (bid & 7) * (nwg >> 3) + (bid >> 3);   // T1 (nwg % 8 == 0)
    const int by = swz / gx, bx = swz - by * gx;
    const int rowbase = by * 128, colbase = bx * 128;
    const int nkt = K >> 6;

    f32x4 acc[4][4];
#pragma unroll
    for (int m = 0; m < 4; m++)
#pragma unroll
        for (int n = 0; n < 4; n++) acc[m][n] = f32x4{0.f, 0.f, 0.f, 0.f};

    for (int kt = 0; kt < nkt; ++kt) {
        if (kt) __builtin_amdgcn_s_barrier();      // prior tile's ds_reads done
        __builtin_amdgcn_sched_barrier(0);
#pragma unroll
        for (int p = 0; p < 4; p++) {
            int s = tid + p * 256;                 // 1024 slots of 16B
            int row = s >> 3, sg = s & 7;
            GLOAD16(Ag + (size_t)(rowbase + row) * K + kt * 64 + ((sg ^ (row & 7)) << 3), &AS[s * 8]);
            GLOAD16(Bg + (size_t)(colbase + row) * K + kt * 64 + ((sg ^ (row & 7)) << 3), &BS[s * 8]);
        }
        asm volatile("s_waitcnt vmcnt(0)" ::: "memory");
        __builtin_amdgcn_s_barrier();

        bf16x8 aF[4][2], bF[4][2];
#pragma unroll
        for (int m = 0; m < 4; m++) {
            int arow = wr * 64 + m * 16 + lrow;
#pragma unroll
            for (int ks = 0; ks < 2; ks++) {
                int sl = (lg + ks * 4) ^ (arow & 7);
                aF[m][ks] = *(const bf16x8*)&AS[arow * 64 + sl * 8];
            }
        }
#pragma unroll
        for (int n = 0; n < 4; n++) {
            int brow = wc * 64 + n * 16 + lrow;
#pragma unroll
            for (int ks = 0; ks < 2; ks++) {
                int sl = (lg + ks * 4) ^ (brow & 7);
                bF[n][ks] = *(const bf16x8*)&BS[brow * 64 + sl * 8];
            }
        }
        asm volatile("s_waitcnt lgkmcnt(0)" ::: "memory");
        __builtin_amdgcn_sched_barrier(0);         // rule #18
        __builtin_amdgcn_s_setprio(1);
#pragma unroll
        for (int m = 0; m < 4; m++)
#pragma unroll
            for (int n = 0; n < 4; n++)
#pragma unroll
                for (int ks = 0; ks < 2; ks++)
                    acc[m][n] = __builtin_amdgcn_mfma_f32_16x16x32_bf16(aF[m][ks], bF[n][ks],
                                                                        acc[m][n], 0, 0, 0);
        __builtin_amdgcn_s_setprio(0);
    }

    // ---- epilogue (bf16 out; V^T split for QKV) ----
    const bool dovt = (vtout != nullptr) && (colbase >= 1024);   // block-uniform
#pragma unroll
    for (int m = 0; m < 4; m++) {
        int row = rowbase + wr * 64 + m * 16 + lg * 4;
#pragma unroll
        for (int n = 0; n < 4; n++) {
            int col = colbase + wc * 64 + n * 16 + lrow;
            float bv = bias ? bias[col] : 0.0f;
            float v[4];
#pragma unroll
            for (int r = 0; r < 4; r++) {
                float x = acc[m][n][r] + bv;
                if (GELU) x = gelu_exact(x);
                v[r] = x;
            }
            if (dovt) {
                int hcol = col - 1024;
                int hh = hcol >> 6, d = hcol & 63;
                int bb = row >> 8, s0 = row & 255;
                u16x4 pk = { bf_bits(v[0]), bf_bits(v[1]), bf_bits(v[2]), bf_bits(v[3]) };
                *(u16x4*)&vtout[((size_t)((bb * 8 + hh) * 64 + d)) * 256 + s0] = pk;
            } else {
#pragma unroll
                for (int r = 0; r < 4; r++)
                    Cb[(size_t)(row + r) * M + col] = (__bf16)v[r];
            }
        }
    }
}

// ---------------------------------------------------------------- MFMA fused attention
// grid: 2048 blocks, XCD-swizzled. Monotone key mask -> block-uniform skip of fully-masked tiles.
__global__ __launch_bounds__(256) void k_attn(const __bf16* __restrict__ QKV,
                                              const uint8_t* __restrict__ ebt,
                                              const float* __restrict__ mskadd,
                                              const __bf16* __restrict__ Vt,
                                              __bf16* __restrict__ T) {
    __shared__ __align__(16) char Ks[8192];
    __shared__ __align__(16) char Vs[8192];
    __shared__ __align__(16) char Ps[4][2048];
    __shared__ float Ma[256];
    const int bid = blockIdx.x;
    const int swzb = (bid & 7) * 256 + (bid >> 3);     // T1, nwg = 2048
    const int bh = swzb >> 2, qt = swzb & 3;
    const int b = bh >> 3, h = bh & 7;
    const int tid = threadIdx.x, wid = tid >> 6, lane = tid & 63;
    const int g = lane >> 4, c = lane & 15;

    Ma[tid] = mskadd[(b << 8) + tid];

    bf16x8 qf[2];
    {
        const __bf16* qrow = QKV + (size_t)((b << 8) + qt * 64 + wid * 16 + c) * 1536 + h * 64;
        qf[0] = *(const bf16x8*)(qrow + g * 8);
        qf[1] = *(const bf16x8*)(qrow + 32 + g * 8);
    }

    f32x4 oacc[4];
    float m_s[4], l_s[4];
#pragma unroll
    for (int r = 0; r < 4; r++) { m_s[r] = -1e30f; l_s[r] = 0.0f; }
#pragma unroll
    for (int nd = 0; nd < 4; nd++) oacc[nd] = f32x4{0.f, 0.f, 0.f, 0.f};

    for (int t = 0; t < 4; t++) {
        const int t0 = t * 64;
        __syncthreads();
        if (t0 > 0 && Ma[t0] < -0.5f) continue;    // monotone mask: whole tile masked
#pragma unroll
        for (int p = 0; p < 2; p++) {
            int idx = tid + p * 256;
            int row = idx >> 3, c8 = idx & 7;
            int lds = row * 128 + ((c8 * 16) ^ ((row & 7) << 4));
            *(uint4*)(Ks + lds) = *(const uint4*)&QKV[(size_t)((b << 8) + t0 + row) * 1536 + 512 + h * 64 + c8 * 8];
            *(uint4*)(Vs + lds) = *(const uint4*)&Vt[((size_t)bh * 64 + row) * 256 + t0 + c8 * 8];
        }
        __syncthreads();

        bf16x8 kf[4][2], vb[4][2];
#pragma unroll
        for (int n = 0; n < 4; n++) {
            int row = n * 16 + c;
#pragma unroll
            for (int ks = 0; ks < 2; ks++) {
                int col = (g * 16 + ks * 64) ^ ((row & 7) << 4);
                kf[n][ks] = *(const bf16x8*)(Ks + row * 128 + col);
                vb[n][ks] = *(const bf16x8*)(Vs + row * 128 + col);
            }
        }

        f32x4 sa[4];
#pragma unroll
        for (int nk = 0; nk < 4; nk++) sa[nk] = f32x4{0.f, 0.f, 0.f, 0.f};
#pragma unroll
        for (int ks = 0; ks < 2; ks++)
#pragma unroll
            for (int nk = 0; nk < 4; nk++)
                sa[nk] = __builtin_amdgcn_mfma_f32_16x16x32_bf16(qf[ks], kf[nk][ks], sa[nk], 0, 0, 0);

        uint4 b4 = *(const uint4*)(ebt + ((((size_t)bh * 4 + t) * 4 + qt) * 4 + wid) * 1024 + c * 64 + g * 16);
        uint32_t bw[4] = { b4.x, b4.y, b4.z, b4.w };
        float s[4][4];                             // [nk][r]
#pragma unroll
        for (int nk = 0; nk < 4; nk++) {
            float ma = Ma[t0 + nk * 16 + c];
#pragma unroll
            for (int r = 0; r < 4; r++)
                s[nk][r] = sa[nk][r] * 0.125f + dec_e4m3((bw[r] >> (nk * 8)) & 0xFF) + ma;
        }

        float corr[4];
#pragma unroll
        for (int r = 0; r < 4; r++) {
            float tm = fmaxf(fmaxf(s[0][r], s[1][r]), fmaxf(s[2][r], s[3][r]));
#pragma unroll
            for (int off = 1; off < 16; off <<= 1)
                tm = fmaxf(tm, __shfl_xor(tm, off));
            float mnew = fmaxf(m_s[r], tm);
            corr[r] = __expf(m_s[r] - mnew);
            m_s[r] = mnew;
            float psum = 0.0f;
#pragma unroll
            for (int nk = 0; nk < 4; nk++) {
                s[nk][r] = __expf(s[nk][r] - mnew);
                psum += s[nk][r];
            }
#pragma unroll
            for (int off = 1; off < 16; off <<= 1)
                psum += __shfl_xor(psum, off);
            l_s[r] = l_s[r] * corr[r] + psum;
        }
#pragma unroll
        for (int nd = 0; nd < 4; nd++)
#pragma unroll
            for (int r = 0; r < 4; r++)
                oacc[nd][r] *= corr[r];

        char* psw = Ps[wid];
#pragma unroll
        for (int r = 0; r < 4; r++) {
            int qs = g * 4 + r;
#pragma unroll
            for (int nk = 0; nk < 4; nk++)
                *(__bf16*)(psw + qs * 128 + ((nk * 32 + c * 2) ^ ((qs & 7) << 4))) = (__bf16)s[nk][r];
        }
        bf16x8 pa[2];
#pragma unroll
        for (int ks = 0; ks < 2; ks++)
            pa[ks] = *(const bf16x8*)(psw + c * 128 + ((g * 16 + ks * 64) ^ ((c & 7) << 4)));
#pragma unroll
        for (int nd = 0; nd < 4; nd++)
#pragma unroll
            for (int ks = 0; ks < 2; ks++)
                oacc[nd] = __builtin_amdgcn_mfma_f32_16x16x32_bf16(pa[ks], vb[nd][ks], oacc[nd], 0, 0, 0);
    }

#pragma unroll
    for (int r = 0; r < 4; r++) {
        float inv = 1.0f / l_s[r];
        size_t rowb = (size_t)((b << 8) + qt * 64 + wid * 16 + g * 4 + r) * 512 + h * 64 + c;
#pragma unroll
        for (int nd = 0; nd < 4; nd++)
            T[rowb + nd * 16] = (__bf16)(oacc[nd][r] * inv);
    }
}

// ---------------------------------------------------------------- fused residual + LayerNorm (bf16 trunk)
// u = Xb + Ob; Xb = bf16(LN(u)). Thread t owns cols 2t, 2t+1.
__global__ __launch_bounds__(256) void k_ln3(const __bf16* __restrict__ Ob,
                                             __bf16* __restrict__ Xb,
                                             const float* __restrict__ g,
                                             const float* __restrict__ bb) {
    __shared__ float red[4];
    int row = blockIdx.x, t = threadIdx.x;
    size_t base = (size_t)row * D_;
    uint ov = *(const uint*)&Ob[base + 2 * t];
    uint xv = *(const uint*)&Xb[base + 2 * t];
    float v0 = bf_val((unsigned short)xv) + bf_val((unsigned short)ov);
    float v1 = bf_val((unsigned short)(xv >> 16)) + bf_val((unsigned short)(ov >> 16));
    float s = wave_sum(v0 + v1);
    if ((t & 63) == 0) red[t >> 6] = s;
    __syncthreads();
    float mean = (red[0] + red[1] + red[2] + red[3]) * (1.0f / D_);
    float d0 = v0 - mean, d1 = v1 - mean;
    float s2 = wave_sum(d0 * d0 + d1 * d1);
    __syncthreads();
    if ((t & 63) == 0) red[t >> 6] = s2;
    __syncthreads();
    float var = (red[0] + red[1] + red[2] + red[3]) * (1.0f / D_);
    float rr = rsqrtf(var + EPS);
    float2 gv = *(const float2*)&g[2 * t];
    float2 bv = *(const float2*)&bb[2 * t];
    float o0 = d0 * rr * gv.x + bv.x;
    float o1 = d1 * rr * gv.y + bv.y;
    uint pk = (uint)bf_bits(o0) | ((uint)bf_bits(o1) << 16);
    *(uint*)&Xb[base + 2 * t] = pk;
}

// ---------------------------------------------------------------- MLP head on CLS (bf16 trunk in)
__global__ __launch_bounds__(256) void k_head(const __bf16* __restrict__ Xb,
                                              const float* __restrict__ W1,
                                              const float* __restrict__ b1,
                                              const float* __restrict__ W2,
                                              const float* __restrict__ b2,
                                              float* __restrict__ out) {
    __shared__ float cls[D_];
    __shared__ float red[4];
    int b = blockIdx.x, t = threadIdx.x;
    size_t base = (size_t)(b << 8) * D_;
    cls[t]       = (float)Xb[base + t];
    cls[t + 256] = (float)Xb[base + t + 256];
    __syncthreads();
    float acc = 0.0f;
    for (int d = 0; d < D_; d++) acc = fmaf(cls[d], W1[(size_t)d * HID_ + t], acc);
    acc += b1[t];
    float hsum = wave_sum(gelu_exact(acc) * W2[t]);
    if ((t & 63) == 0) red[t >> 6] = hsum;
    __syncthreads();
    if (t == 0) out[b] = red[0] + red[1] + red[2] + red[3] + b2[0];
}

// ---------------------------------------------------------------- launch
extern "C" void kernel_launch(void* const* d_in, const int* in_sizes, int n_in,
                              void* d_out, int out_size, void* d_ws, size_t ws_size,
                              hipStream_t stream) {
    const float* atom = (const float*)d_in[0];
    const float* eb   = (const float*)d_in[1];
    const void*  mraw = d_in[2];
    const float* cls  = (const float*)d_in[3];
    const float* Wq = (const float*)d_in[4];  const float* bq = (const float*)d_in[5];
    const float* Wk = (const float*)d_in[6];  const float* bk = (const float*)d_in[7];
    const float* Wv = (const float*)d_in[8];  const float* bv = (const float*)d_in[9];
    const float* Wo = (const float*)d_in[10]; const float* bo = (const float*)d_in[11];
    const float* g1 = (const float*)d_in[12]; const float* be1 = (const float*)d_in[13];
    const float* W1 = (const float*)d_in[14]; const float* b1 = (const float*)d_in[15];
    const float* W2 = (const float*)d_in[16]; const float* b2 = (const float*)d_in[17];
    const float* g2 = (const float*)d_in[18]; const float* be2 = (const float*)d_in[19];
    const float* hW1 = (const float*)d_in[20]; const float* hb1 = (const float*)d_in[21];
    const float* hW2 = (const float*)d_in[22]; const float* hb2 = (const float*)d_in[23];
    float* out = (float*)d_out;

    // ---- workspace layout ----
    char* p = (char*)d_ws;
    __bf16* Xb    = (__bf16*)p;                p += (size_t)N_ * D_ * 2;        // bf16 residual trunk
    __bf16* Vt    = (__bf16*)p;                p += (size_t)N_ * D_ * 2;        // V^T (QKV->attn)
    __bf16* Ob    = (__bf16*)p;                p += (size_t)N_ * D_ * 2;        // GEMM bf16 out (O/FFN2 -> ln3)
    char*   R     = p;                         p += (size_t)N_ * FF_ * 2;
    __bf16* QKVb  = (__bf16*)R;                                                 // [N][1536]
    __bf16* Tb    = (__bf16*)(R + (size_t)N_ * 1536 * 2);                       // [N][512]
    __bf16* Hb    = (__bf16*)R;                                                 // [N][2048]
    uint8_t* ebt  = (uint8_t*)p;               p += (size_t)B_ * H_ * SP * SP;  // fragment-layout fp8
    __bf16* Wqkvt = (__bf16*)p;                p += (size_t)L_ * 1536 * 512 * 2;
    __bf16* Wot   = (__bf16*)p;                p += (size_t)L_ * 512 * 512 * 2;
    __bf16* W1t   = (__bf16*)p;                p += (size_t)L_ * 2048 * 512 * 2;
    __bf16* W2t   = (__bf16*)p;                p += (size_t)L_ * 512 * 2048 * 2;
    float*  bqkv  = (float*)p;                 p += (size_t)L_ * 1536 * 4;
    float*  mskadd= (float*)p;                 p += (size_t)B_ * SP * 4;
    int* flag = (int*)p;

    // ---- prep ----
    hipMemsetAsync(flag, 0, 4, stream);
    k_mask_detect<<<16, 256, 0, stream>>>((const unsigned int*)mraw, (B_ * S_) / 4, flag);
    k_mask_prep<<<(B_ * SP) / 256, 256, 0, stream>>>(mraw, flag, mskadd);
    k_bcat<<<(L_ * 1536) / 256, 256, 0, stream>>>(bq, bk, bv, bqkv);
    k_wt<<<dim3(8, 8, L_),  256, 0, stream>>>(Wq, Wqkvt, 512, 512, 0,    262144, 786432);
    k_wt<<<dim3(8, 8, L_),  256, 0, stream>>>(Wk, Wqkvt, 512, 512, 512,  262144, 786432);
    k_wt<<<dim3(8, 8, L_),  256, 0, stream>>>(Wv, Wqkvt, 512, 512, 1024, 262144, 786432);
    k_wt<<<dim3(8, 8, L_),  256, 0, stream>>>(Wo, Wot,   512, 512, 0,    262144, 262144);
    k_wt<<<dim3(32, 8, L_), 256, 0, stream>>>(W1, W1t,   512, 2048, 0,   1048576, 1048576);
    k_wt<<<dim3(8, 32, L_), 256, 0, stream>>>(W2, W2t,   2048, 512, 0,   1048576, 1048576);
    k_ebt5<<<B_ * 16, 256, 0, stream>>>(eb, ebt);
    k_build_x<<<(N_ * D_) / 256, 256, 0, stream>>>(atom, cls, Xb);

    for (int l = 0; l < L_; l++) {
        k_gemm2<0><<<1536, 256, 0, stream>>>(Xb, Wqkvt + (size_t)l * 786432, bqkv + l * 1536,
                                             QKVb, Vt, 512, 1536, 12);
        k_attn<<<B_ * H_ * 4, 256, 0, stream>>>(QKVb, ebt, mskadd, Vt, Tb);
        k_gemm2<0><<<512, 256, 0, stream>>>(Tb, Wot + (size_t)l * 262144, bo + l * 512,
                                            Ob, nullptr, 512, 512, 4);
        k_ln3<<<N_, 256, 0, stream>>>(Ob, Xb, g1 + l * D_, be1 + l * D_);
        k_gemm2<1><<<2048, 256, 0, stream>>>(Xb, W1t + (size_t)l * 1048576, b1 + l * FF_,
                                             Hb, nullptr, 512, 2048, 16);
        k_gemm2<0><<<512, 256, 0, stream>>>(Hb, W2t + (size_t)l * 1048576, b2 + l * D_,
                                            Ob, nullptr, 2048, 512, 4);
        k_ln3<<<N_, 256, 0, stream>>>(Ob, Xb, g2 + l * D_, be2 + l * D_);
    }
    k_head<<<B_, 256, 0, stream>>>(Xb, hW1, hb1, hW2, hb2, out);
}

// Round 13
// 1466.324 us; speedup vs baseline: 4.9139x; 1.0848x over previous
//
#include <hip/hip_runtime.h>
#include <math.h>
#include <stdint.h>

#define B_   64
#define S_   255
#define SP   256
#define D_   512
#define H_   8
#define L_   6
#define FF_  2048
#define HID_ 256
#define N_   (B_*SP)       // 16384 rows
#define EPS  1e-5f

using bf16x8 = __bf16 __attribute__((ext_vector_type(8)));
using f32x4  = float __attribute__((ext_vector_type(4)));
using u16x4  = unsigned short __attribute__((ext_vector_type(4)));

// ---------------------------------------------------------------- utilities
__device__ inline float wave_sum(float v) {
#pragma unroll
    for (int off = 32; off; off >>= 1) v += __shfl_xor(v, off);
    return v;
}

// fast exact-erf gelu: A&S 7.1.26 polynomial, |erf err| <= 1.5e-7
__device__ inline float gelu_exact(float x) {
    float z  = fabsf(x) * 0.70710678118654752f;
    float tt = __builtin_amdgcn_rcpf(fmaf(0.3275911f, z, 1.0f));
    float poly = tt * (0.254829592f + tt * (-0.284496736f + tt * (1.421413741f +
                 tt * (-1.453152027f + tt * 1.061405429f))));
    float er = 1.0f - poly * __expf(-z * z);
    er = copysignf(er, x);
    return 0.5f * x * (1.0f + er);
}

__device__ inline unsigned short bf_bits(float x) {
    __bf16 h = (__bf16)x;
    return *(unsigned short*)&h;
}

__device__ inline float bf_val(unsigned short u) {
    __bf16 h = *(__bf16*)&u;
    return (float)h;
}

// fp8 e4m3fn encode (RNE) / decode
__device__ inline uint8_t enc_e4m3(float f) {
    uint32_t u = __float_as_uint(f);
    uint32_t s = (u >> 24) & 0x80u;
    float a = fabsf(f);
    if (a < 0.015625f) {
        int m = (int)rintf(a * 512.0f);
        if (m >= 8) return (uint8_t)(s | 0x08);
        return (uint8_t)(s | (uint32_t)m);
    }
    if (a > 448.0f) return (uint8_t)(s | 0x7E);
    uint32_t b = __float_as_uint(a);
    uint32_t expf_ = b >> 23;
    uint32_t mant = b & 0x7FFFFF;
    uint32_t keep = mant >> 20;
    uint32_t rest = mant & 0xFFFFF;
    if (rest > 0x80000u || (rest == 0x80000u && (keep & 1))) keep++;
    if (keep == 8) { keep = 0; expf_++; }
    int e8 = (int)expf_ - 120;
    if (e8 >= 16) return (uint8_t)(s | 0x7E);
    return (uint8_t)(s | ((uint32_t)e8 << 3) | keep);
}

__device__ inline float dec_e4m3(uint32_t b) {
    uint32_t mag = b & 0x7Fu;
    float fm = __uint_as_float((mag << 20) + (120u << 23));
    if ((mag >> 3) == 0) fm = fm * 2.0f - 0.015625f;
    return (b & 0x80u) ? -fm : fm;
}

// async global->LDS 16B (m97 recipe)
#define GLOAD16(gsrc, ldst) \
    __builtin_amdgcn_global_load_lds((const __attribute__((address_space(1))) unsigned int*)(gsrc), \
                                     (__attribute__((address_space(3))) unsigned int*)(ldst), 16, 0, 0)

// ---------------------------------------------------------------- build Xb = [cls; atom] (bf16 trunk)
__global__ void k_build_x(const float* __restrict__ atom, const float* __restrict__ cls,
                          __bf16* __restrict__ Xb) {
    int idx = blockIdx.x * 256 + threadIdx.x;
    int col = idx & (D_ - 1);
    int row = idx >> 9;
    int sr  = row & (SP - 1);
    int b   = row >> 8;
    float v = (sr == 0) ? cls[col] : atom[((size_t)(b * S_) + (sr - 1)) * D_ + col];
    Xb[idx] = (__bf16)v;
}

// ---------------------------------------------------------------- mask layout detection
__global__ void k_mask_detect(const unsigned int* __restrict__ mw, int nw, int* flag) {
    int i = blockIdx.x * 256 + threadIdx.x;
    if (i < nw && mw[i] > 1u) atomicOr(flag, 1);
}

__global__ void k_mask_prep(const void* __restrict__ mraw, const int* __restrict__ flag,
                            float* __restrict__ mskadd) {
    int i = blockIdx.x * 256 + threadIdx.x;
    int b = i >> 8, j = i & 255;
    float v = 0.0f;
    if (j > 0) {
        int src = b * S_ + (j - 1);
        bool m = (*flag) ? (((const unsigned char*)mraw)[src] != 0)
                         : (((const int*)mraw)[src] != 0);
        if (m) v = -1e30f;
    }
    mskadd[i] = v;
}

// ---------------------------------------------------------------- weight transpose+cast
__global__ __launch_bounds__(256) void k_wt(const float* __restrict__ W, __bf16* __restrict__ Wt,
                                            int K, int Mw, int mout_off,
                                            size_t in_lstride, size_t out_lstride) {
    __shared__ float T[64][65];
    int l = blockIdx.z;
    int m0 = blockIdx.x * 64, k0 = blockIdx.y * 64;
    const float* Wl = W + (size_t)l * in_lstride;
    __bf16* Wtl = Wt + (size_t)l * out_lstride;
    int tid = threadIdx.x;
    int cc = tid & 63, rr = tid >> 6;
#pragma unroll
    for (int p = 0; p < 16; p++) {
        int kk = rr + p * 4;
        T[kk][cc] = Wl[(size_t)(k0 + kk) * Mw + m0 + cc];
    }
    __syncthreads();
#pragma unroll
    for (int p = 0; p < 16; p++) {
        int mm = rr + p * 4;
        Wtl[(size_t)(mout_off + m0 + mm) * K + k0 + cc] = (__bf16)T[cc][mm];
    }
}

// ---------------------------------------------------------------- qkv bias concat
__global__ void k_bcat(const float* __restrict__ bq, const float* __restrict__ bk,
                       const float* __restrict__ bv, float* __restrict__ bqkv) {
    int i = blockIdx.x * 256 + threadIdx.x;
    int l = i / 1536, c = i % 1536;
    float v;
    if (c < 512)       v = bq[l * 512 + c];
    else if (c < 1024) v = bk[l * 512 + c - 512];
    else               v = bv[l * 512 + c - 1024];
    bqkv[i] = v;
}

// ---------------------------------------------------------------- bias repack, coalesced both sides
__global__ __launch_bounds__(256) void k_ebt5(const float* __restrict__ eb, uint8_t* __restrict__ ebt) {
    __shared__ uint8_t Ls[8 * 16 * 260];           // [h][qi][260], odd-dword qi stride
    int blk = blockIdx.x;                          // 64*16
    int b = blk >> 4, wm = blk & 15;
    int w = wm >> 2, mq = wm & 3;
    int qbase = w * 64 + mq * 16;
    int t = threadIdx.x;
    for (int qi = 0; qi < 16; qi++) {
        int q = qbase + qi;
        if (q > 0) {
            const float4* src = (const float4*)(eb + ((size_t)(b * 255) + (q - 1)) * 2040);
#pragma unroll
            for (int p = 0; p < 2; p++) {
                int idx4 = t + p * 256;
                if (idx4 < 510) {
                    float4 v = src[idx4];
                    int k  = idx4 >> 1;
                    int h0 = (idx4 & 1) * 4;
                    Ls[((h0 + 0) * 16 + qi) * 260 + k] = enc_e4m3(v.x);
                    Ls[((h0 + 1) * 16 + qi) * 260 + k] = enc_e4m3(v.y);
                    Ls[((h0 + 2) * 16 + qi) * 260 + k] = enc_e4m3(v.z);
                    Ls[((h0 + 3) * 16 + qi) * 260 + k] = enc_e4m3(v.w);
                }
            }
        }
    }
    __syncthreads();
    int cc = t >> 4, qi = t & 15;
    int q = qbase + qi;
    uint32_t* outp = (uint32_t*)ebt;
#pragma unroll
    for (int h = 0; h < 8; h++) {
#pragma unroll
        for (int tl = 0; tl < 4; tl++) {
            uint32_t d = 0;
            if (q > 0) {
#pragma unroll
                for (int nk = 0; nk < 4; nk++) {
                    int k = tl * 64 + nk * 16 + cc;
                    if (k > 0) d |= (uint32_t)Ls[(h * 16 + qi) * 260 + (k - 1)] << (nk * 8);
                }
            }
            size_t x = ((((size_t)(b * 8 + h) * 4 + tl) * 4 + w) * 4 + mq) * 256 + t;
            outp[x] = d;
        }
    }
}

// ---------------------------------------------------------------- 128x128 single-buffer MFMA GEMM, 8 waves
// Round-12 post-mortem: with 4 waves/block the per-wave footprint is 88 VGPR + 64 AGPR acc
// (~152 unified regs) -> only 2 blocks/CU resident -> latency-bound at MfmaUtil 18%.
// 8 waves (512 thr), per-wave 64x32 output: acc 32 + frags 48 => ~107 regs -> 4 waves/SIMD.
// __launch_bounds__(512,2): measured cap rule is ~256/min_waves (48@5, 64@4, 88@2) -> cap 128, no spill.
// T1 XCD swizzle; T2 both-sides XOR involution; T5 setprio; 32 KB LDS.
template<int GELU>
__global__ __launch_bounds__(512, 2) void k_gemm2(const __bf16* __restrict__ Ag,
                                                  const __bf16* __restrict__ Bg,
                                                  const float* __restrict__ bias,
                                                  __bf16* __restrict__ Cb,
                                                  __bf16* __restrict__ vtout,
                                                  int K, int M, int gx) {
    __shared__ __align__(16) __bf16 AS[128 * 64];
    __shared__ __align__(16) __bf16 BS[128 * 64];
    const int tid = threadIdx.x;
    const int w = tid >> 6, lane = tid & 63;
    const int wr = w >> 2, wc = w & 3;             // 2 row-groups x 4 col-groups
    const int lrow = lane & 15, lg = lane >> 4;
    const int nwg = gridDim.x, bid = blockIdx.x;
    const int swz = (bid & 7) * (nwg >> 3) + (bid >> 3);   // T1 (nwg % 8 == 0)
    const int by = swz / gx, bx = swz - by * gx;
    const int rowbase = by * 128, colbase = bx * 128;
    const int nkt = K >> 6;

    f32x4 acc[4][2];
#pragma unroll
    for (int m = 0; m < 4; m++)
#pragma unroll
        for (int n = 0; n < 2; n++) acc[m][n] = f32x4{0.f, 0.f, 0.f, 0.f};

    for (int kt = 0; kt < nkt; ++kt) {
        if (kt) __builtin_amdgcn_s_barrier();      // prior tile's ds_reads done
        __builtin_amdgcn_sched_barrier(0);
#pragma unroll
        for (int p = 0; p < 2; p++) {
            int s = tid + p * 512;                 // 1024 slots of 16B
            int row = s >> 3, sg = s & 7;
            GLOAD16(Ag + (size_t)(rowbase + row) * K + kt * 64 + ((sg ^ (row & 7)) << 3), &AS[s * 8]);
            GLOAD16(Bg + (size_t)(colbase + row) * K + kt * 64 + ((sg ^ (row & 7)) << 3), &BS[s * 8]);
        }
        asm volatile("s_waitcnt vmcnt(0)" ::: "memory");
        __builtin_amdgcn_s_barrier();

        bf16x8 aF[4][2], bF[2][2];
#pragma unroll
        for (int m = 0; m < 4; m++) {
            int arow = wr * 64 + m * 16 + lrow;
#pragma unroll
            for (int ks = 0; ks < 2; ks++) {
                int sl = (lg + ks * 4) ^ (arow & 7);
                aF[m][ks] = *(const bf16x8*)&AS[arow * 64 + sl * 8];
            }
        }
#pragma unroll
        for (int n = 0; n < 2; n++) {
            int brow = wc * 32 + n * 16 + lrow;
#pragma unroll
            for (int ks = 0; ks < 2; ks++) {
                int sl = (lg + ks * 4) ^ (brow & 7);
                bF[n][ks] = *(const bf16x8*)&BS[brow * 64 + sl * 8];
            }
        }
        asm volatile("s_waitcnt lgkmcnt(0)" ::: "memory");
        __builtin_amdgcn_sched_barrier(0);         // rule #18
        __builtin_amdgcn_s_setprio(1);
#pragma unroll
        for (int m = 0; m < 4; m++)
#pragma unroll
            for (int n = 0; n < 2; n++)
#pragma unroll
                for (int ks = 0; ks < 2; ks++)
                    acc[m][n] = __builtin_amdgcn_mfma_f32_16x16x32_bf16(aF[m][ks], bF[n][ks],
                                                                        acc[m][n], 0, 0, 0);
        __builtin_amdgcn_s_setprio(0);
    }

    // ---- epilogue (bf16 out; V^T split for QKV) ----
    const bool dovt = (vtout != nullptr) && (colbase >= 1024);   // block-uniform
#pragma unroll
    for (int m = 0; m < 4; m++) {
        int row = rowbase + wr * 64 + m * 16 + lg * 4;
#pragma unroll
        for (int n = 0; n < 2; n++) {
            int col = colbase + wc * 32 + n * 16 + lrow;
            float bv = bias ? bias[col] : 0.0f;
            float v[4];
#pragma unroll
            for (int r = 0; r < 4; r++) {
                float x = acc[m][n][r] + bv;
                if (GELU) x = gelu_exact(x);
                v[r] = x;
            }
            if (dovt) {
                int hcol = col - 1024;
                int hh = hcol >> 6, d = hcol & 63;
                int bb = row >> 8, s0 = row & 255;
                u16x4 pk = { bf_bits(v[0]), bf_bits(v[1]), bf_bits(v[2]), bf_bits(v[3]) };
                *(u16x4*)&vtout[((size_t)((bb * 8 + hh) * 64 + d)) * 256 + s0] = pk;
            } else {
#pragma unroll
                for (int r = 0; r < 4; r++)
                    Cb[(size_t)(row + r) * M + col] = (__bf16)v[r];
            }
        }
    }
}

// ---------------------------------------------------------------- MFMA fused attention
// grid: 2048 blocks, XCD-swizzled. Monotone key mask -> block-uniform skip of fully-masked tiles.
__global__ __launch_bounds__(256) void k_attn(const __bf16* __restrict__ QKV,
                                              const uint8_t* __restrict__ ebt,
                                              const float* __restrict__ mskadd,
                                              const __bf16* __restrict__ Vt,
                                              __bf16* __restrict__ T) {
    __shared__ __align__(16) char Ks[8192];
    __shared__ __align__(16) char Vs[8192];
    __shared__ __align__(16) char Ps[4][2048];
    __shared__ float Ma[256];
    const int bid = blockIdx.x;
    const int swzb = (bid & 7) * 256 + (bid >> 3);     // T1, nwg = 2048
    const int bh = swzb >> 2, qt = swzb & 3;
    const int b = bh >> 3, h = bh & 7;
    const int tid = threadIdx.x, wid = tid >> 6, lane = tid & 63;
    const int g = lane >> 4, c = lane & 15;

    Ma[tid] = mskadd[(b << 8) + tid];

    bf16x8 qf[2];
    {
        const __bf16* qrow = QKV + (size_t)((b << 8) + qt * 64 + wid * 16 + c) * 1536 + h * 64;
        qf[0] = *(const bf16x8*)(qrow + g * 8);
        qf[1] = *(const bf16x8*)(qrow + 32 + g * 8);
    }

    f32x4 oacc[4];
    float m_s[4], l_s[4];
#pragma unroll
    for (int r = 0; r < 4; r++) { m_s[r] = -1e30f; l_s[r] = 0.0f; }
#pragma unroll
    for (int nd = 0; nd < 4; nd++) oacc[nd] = f32x4{0.f, 0.f, 0.f, 0.f};

    for (int t = 0; t < 4; t++) {
        const int t0 = t * 64;
        __syncthreads();
        if (t0 > 0 && Ma[t0] < -0.5f) continue;    // monotone mask: whole tile masked
#pragma unroll
        for (int p = 0; p < 2; p++) {
            int idx = tid + p * 256;
            int row = idx >> 3, c8 = idx & 7;
            int lds = row * 128 + ((c8 * 16) ^ ((row & 7) << 4));
            *(uint4*)(Ks + lds) = *(const uint4*)&QKV[(size_t)((b << 8) + t0 + row) * 1536 + 512 + h * 64 + c8 * 8];
            *(uint4*)(Vs + lds) = *(const uint4*)&Vt[((size_t)bh * 64 + row) * 256 + t0 + c8 * 8];
        }
        __syncthreads();

        bf16x8 kf[4][2], vb[4][2];
#pragma unroll
        for (int n = 0; n < 4; n++) {
            int row = n * 16 + c;
#pragma unroll
            for (int ks = 0; ks < 2; ks++) {
                int col = (g * 16 + ks * 64) ^ ((row & 7) << 4);
                kf[n][ks] = *(const bf16x8*)(Ks + row * 128 + col);
                vb[n][ks] = *(const bf16x8*)(Vs + row * 128 + col);
            }
        }

        f32x4 sa[4];
#pragma unroll
        for (int nk = 0; nk < 4; nk++) sa[nk] = f32x4{0.f, 0.f, 0.f, 0.f};
#pragma unroll
        for (int ks = 0; ks < 2; ks++)
#pragma unroll
            for (int nk = 0; nk < 4; nk++)
                sa[nk] = __builtin_amdgcn_mfma_f32_16x16x32_bf16(qf[ks], kf[nk][ks], sa[nk], 0, 0, 0);

        uint4 b4 = *(const uint4*)(ebt + ((((size_t)bh * 4 + t) * 4 + qt) * 4 + wid) * 1024 + c * 64 + g * 16);
        uint32_t bw[4] = { b4.x, b4.y, b4.z, b4.w };
        float s[4][4];                             // [nk][r]
#pragma unroll
        for (int nk = 0; nk < 4; nk++) {
            float ma = Ma[t0 + nk * 16 + c];
#pragma unroll
            for (int r = 0; r < 4; r++)
                s[nk][r] = sa[nk][r] * 0.125f + dec_e4m3((bw[r] >> (nk * 8)) & 0xFF) + ma;
        }

        float corr[4];
#pragma unroll
        for (int r = 0; r < 4; r++) {
            float tm = fmaxf(fmaxf(s[0][r], s[1][r]), fmaxf(s[2][r], s[3][r]));
#pragma unroll
            for (int off = 1; off < 16; off <<= 1)
                tm = fmaxf(tm, __shfl_xor(tm, off));
            float mnew = fmaxf(m_s[r], tm);
            corr[r] = __expf(m_s[r] - mnew);
            m_s[r] = mnew;
            float psum = 0.0f;
#pragma unroll
            for (int nk = 0; nk < 4; nk++) {
                s[nk][r] = __expf(s[nk][r] - mnew);
                psum += s[nk][r];
            }
#pragma unroll
            for (int off = 1; off < 16; off <<= 1)
                psum += __shfl_xor(psum, off);
            l_s[r] = l_s[r] * corr[r] + psum;
        }
#pragma unroll
        for (int nd = 0; nd < 4; nd++)
#pragma unroll
            for (int r = 0; r < 4; r++)
                oacc[nd][r] *= corr[r];

        char* psw = Ps[wid];
#pragma unroll
        for (int r = 0; r < 4; r++) {
            int qs = g * 4 + r;
#pragma unroll
            for (int nk = 0; nk < 4; nk++)
                *(__bf16*)(psw + qs * 128 + ((nk * 32 + c * 2) ^ ((qs & 7) << 4))) = (__bf16)s[nk][r];
        }
        bf16x8 pa[2];
#pragma unroll
        for (int ks = 0; ks < 2; ks++)
            pa[ks] = *(const bf16x8*)(psw + c * 128 + ((g * 16 + ks * 64) ^ ((c & 7) << 4)));
#pragma unroll
        for (int nd = 0; nd < 4; nd++)
#pragma unroll
            for (int ks = 0; ks < 2; ks++)
                oacc[nd] = __builtin_amdgcn_mfma_f32_16x16x32_bf16(pa[ks], vb[nd][ks], oacc[nd], 0, 0, 0);
    }

#pragma unroll
    for (int r = 0; r < 4; r++) {
        float inv = 1.0f / l_s[r];
        size_t rowb = (size_t)((b << 8) + qt * 64 + wid * 16 + g * 4 + r) * 512 + h * 64 + c;
#pragma unroll
        for (int nd = 0; nd < 4; nd++)
            T[rowb + nd * 16] = (__bf16)(oacc[nd][r] * inv);
    }
}

// ---------------------------------------------------------------- fused residual + LayerNorm (bf16 trunk)
__global__ __launch_bounds__(256) void k_ln3(const __bf16* __restrict__ Ob,
                                             __bf16* __restrict__ Xb,
                                             const float* __restrict__ g,
                                             const float* __restrict__ bb) {
    __shared__ float red[4];
    int row = blockIdx.x, t = threadIdx.x;
    size_t base = (size_t)row * D_;
    uint ov = *(const uint*)&Ob[base + 2 * t];
    uint xv = *(const uint*)&Xb[base + 2 * t];
    float v0 = bf_val((unsigned short)xv) + bf_val((unsigned short)ov);
    float v1 = bf_val((unsigned short)(xv >> 16)) + bf_val((unsigned short)(ov >> 16));
    float s = wave_sum(v0 + v1);
    if ((t & 63) == 0) red[t >> 6] = s;
    __syncthreads();
    float mean = (red[0] + red[1] + red[2] + red[3]) * (1.0f / D_);
    float d0 = v0 - mean, d1 = v1 - mean;
    float s2 = wave_sum(d0 * d0 + d1 * d1);
    __syncthreads();
    if ((t & 63) == 0) red[t >> 6] = s2;
    __syncthreads();
    float var = (red[0] + red[1] + red[2] + red[3]) * (1.0f / D_);
    float rr = rsqrtf(var + EPS);
    float2 gv = *(const float2*)&g[2 * t];
    float2 bv = *(const float2*)&bb[2 * t];
    float o0 = d0 * rr * gv.x + bv.x;
    float o1 = d1 * rr * gv.y + bv.y;
    uint pk = (uint)bf_bits(o0) | ((uint)bf_bits(o1) << 16);
    *(uint*)&Xb[base + 2 * t] = pk;
}

// ---------------------------------------------------------------- MLP head on CLS (bf16 trunk in)
__global__ __launch_bounds__(256) void k_head(const __bf16* __restrict__ Xb,
                                              const float* __restrict__ W1,
                                              const float* __restrict__ b1,
                                              const float* __restrict__ W2,
                                              const float* __restrict__ b2,
                                              float* __restrict__ out) {
    __shared__ float cls[D_];
    __shared__ float red[4];
    int b = blockIdx.x, t = threadIdx.x;
    size_t base = (size_t)(b << 8) * D_;
    cls[t]       = (float)Xb[base + t];
    cls[t + 256] = (float)Xb[base + t + 256];
    __syncthreads();
    float acc = 0.0f;
    for (int d = 0; d < D_; d++) acc = fmaf(cls[d], W1[(size_t)d * HID_ + t], acc);
    acc += b1[t];
    float hsum = wave_sum(gelu_exact(acc) * W2[t]);
    if ((t & 63) == 0) red[t >> 6] = hsum;
    __syncthreads();
    if (t == 0) out[b] = red[0] + red[1] + red[2] + red[3] + b2[0];
}

// ---------------------------------------------------------------- launch
extern "C" void kernel_launch(void* const* d_in, const int* in_sizes, int n_in,
                              void* d_out, int out_size, void* d_ws, size_t ws_size,
                              hipStream_t stream) {
    const float* atom = (const float*)d_in[0];
    const float* eb   = (const float*)d_in[1];
    const void*  mraw = d_in[2];
    const float* cls  = (const float*)d_in[3];
    const float* Wq = (const float*)d_in[4];  const float* bq = (const float*)d_in[5];
    const float* Wk = (const float*)d_in[6];  const float* bk = (const float*)d_in[7];
    const float* Wv = (const float*)d_in[8];  const float* bv = (const float*)d_in[9];
    const float* Wo = (const float*)d_in[10]; const float* bo = (const float*)d_in[11];
    const float* g1 = (const float*)d_in[12]; const float* be1 = (const float*)d_in[13];
    const float* W1 = (const float*)d_in[14]; const float* b1 = (const float*)d_in[15];
    const float* W2 = (const float*)d_in[16]; const float* b2 = (const float*)d_in[17];
    const float* g2 = (const float*)d_in[18]; const float* be2 = (const float*)d_in[19];
    const float* hW1 = (const float*)d_in[20]; const float* hb1 = (const float*)d_in[21];
    const float* hW2 = (const float*)d_in[22]; const float* hb2 = (const float*)d_in[23];
    float* out = (float*)d_out;

    // ---- workspace layout ----
    char* p = (char*)d_ws;
    __bf16* Xb    = (__bf16*)p;                p += (size_t)N_ * D_ * 2;        // bf16 residual trunk
    __bf16* Vt    = (__bf16*)p;                p += (size_t)N_ * D_ * 2;        // V^T (QKV->attn)
    __bf16* Ob    = (__bf16*)p;                p += (size_t)N_ * D_ * 2;        // GEMM bf16 out (O/FFN2 -> ln3)
    char*   R     = p;                         p += (size_t)N_ * FF_ * 2;
    __bf16* QKVb  = (__bf16*)R;                                                 // [N][1536]
    __bf16* Tb    = (__bf16*)(R + (size_t)N_ * 1536 * 2);                       // [N][512]
    __bf16* Hb    = (__bf16*)R;                                                 // [N][2048]
    uint8_t* ebt  = (uint8_t*)p;               p += (size_t)B_ * H_ * SP * SP;  // fragment-layout fp8
    __bf16* Wqkvt = (__bf16*)p;                p += (size_t)L_ * 1536 * 512 * 2;
    __bf16* Wot   = (__bf16*)p;                p += (size_t)L_ * 512 * 512 * 2;
    __bf16* W1t   = (__bf16*)p;                p += (size_t)L_ * 2048 * 512 * 2;
    __bf16* W2t   = (__bf16*)p;                p += (size_t)L_ * 512 * 2048 * 2;
    float*  bqkv  = (float*)p;                 p += (size_t)L_ * 1536 * 4;
    float*  mskadd= (float*)p;                 p += (size_t)B_ * SP * 4;
    int* flag = (int*)p;

    // ---- prep ----
    hipMemsetAsync(flag, 0, 4, stream);
    k_mask_detect<<<16, 256, 0, stream>>>((const unsigned int*)mraw, (B_ * S_) / 4, flag);
    k_mask_prep<<<(B_ * SP) / 256, 256, 0, stream>>>(mraw, flag, mskadd);
    k_bcat<<<(L_ * 1536) / 256, 256, 0, stream>>>(bq, bk, bv, bqkv);
    k_wt<<<dim3(8, 8, L_),  256, 0, stream>>>(Wq, Wqkvt, 512, 512, 0,    262144, 786432);
    k_wt<<<dim3(8, 8, L_),  256, 0, stream>>>(Wk, Wqkvt, 512, 512, 512,  262144, 786432);
    k_wt<<<dim3(8, 8, L_),  256, 0, stream>>>(Wv, Wqkvt, 512, 512, 1024, 262144, 786432);
    k_wt<<<dim3(8, 8, L_),  256, 0, stream>>>(Wo, Wot,   512, 512, 0,    262144, 262144);
    k_wt<<<dim3(32, 8, L_), 256, 0, stream>>>(W1, W1t,   512, 2048, 0,   1048576, 1048576);
    k_wt<<<dim3(8, 32, L_), 256, 0, stream>>>(W2, W2t,   2048, 512, 0,   1048576, 1048576);
    k_ebt5<<<B_ * 16, 256, 0, stream>>>(eb, ebt);
    k_build_x<<<(N_ * D_) / 256, 256, 0, stream>>>(atom, cls, Xb);

    for (int l = 0; l < L_; l++) {
        k_gemm2<0><<<1536, 512, 0, stream>>>(Xb, Wqkvt + (size_t)l * 786432, bqkv + l * 1536,
                                             QKVb, Vt, 512, 1536, 12);
        k_attn<<<B_ * H_ * 4, 256, 0, stream>>>(QKVb, ebt, mskadd, Vt, Tb);
        k_gemm2<0><<<512, 512, 0, stream>>>(Tb, Wot + (size_t)l * 262144, bo + l * 512,
                                            Ob, nullptr, 512, 512, 4);
        k_ln3<<<N_, 256, 0, stream>>>(Ob, Xb, g1 + l * D_, be1 + l * D_);
        k_gemm2<1><<<2048, 512, 0, stream>>>(Xb, W1t + (size_t)l * 1048576, b1 + l * FF_,
                                             Hb, nullptr, 512, 2048, 16);
        k_gemm2<0><<<512, 512, 0, stream>>>(Hb, W2t + (size_t)l * 1048576, b2 + l * D_,
                                            Ob, nullptr, 2048, 512, 4);
        k_ln3<<<N_, 256, 0, stream>>>(Ob, Xb, g2 + l * D_, be2 + l * D_);
    }
    k_head<<<B_, 256, 0, stream>>>(Xb, hW1, hb1, hW2, hb2, out);
}

// Round 14
// 1442.777 us; speedup vs baseline: 4.9941x; 1.0163x over previous
//
#include <hip/hip_runtime.h>
#include <math.h>
#include <stdint.h>

#define B_   64
#define S_   255
#define SP   256
#define D_   512
#define H_   8
#define L_   6
#define FF_  2048
#define HID_ 256
#define N_   (B_*SP)       // 16384 rows
#define EPS  1e-5f

using bf16x8 = __bf16 __attribute__((ext_vector_type(8)));
using f32x4  = float __attribute__((ext_vector_type(4)));
using u16x4  = unsigned short __attribute__((ext_vector_type(4)));

// ---------------------------------------------------------------- utilities
__device__ inline float wave_sum(float v) {
#pragma unroll
    for (int off = 32; off; off >>= 1) v += __shfl_xor(v, off);
    return v;
}

// fast exact-erf gelu: A&S 7.1.26 polynomial, |erf err| <= 1.5e-7
__device__ inline float gelu_exact(float x) {
    float z  = fabsf(x) * 0.70710678118654752f;
    float tt = __builtin_amdgcn_rcpf(fmaf(0.3275911f, z, 1.0f));
    float poly = tt * (0.254829592f + tt * (-0.284496736f + tt * (1.421413741f +
                 tt * (-1.453152027f + tt * 1.061405429f))));
    float er = 1.0f - poly * __expf(-z * z);
    er = copysignf(er, x);
    return 0.5f * x * (1.0f + er);
}

__device__ inline unsigned short bf_bits(float x) {
    __bf16 h = (__bf16)x;
    return *(unsigned short*)&h;
}

__device__ inline float bf_val(unsigned short u) {
    __bf16 h = *(__bf16*)&u;
    return (float)h;
}

// fp8 e4m3fn encode (RNE) / decode
__device__ inline uint8_t enc_e4m3(float f) {
    uint32_t u = __float_as_uint(f);
    uint32_t s = (u >> 24) & 0x80u;
    float a = fabsf(f);
    if (a < 0.015625f) {
        int m = (int)rintf(a * 512.0f);
        if (m >= 8) return (uint8_t)(s | 0x08);
        return (uint8_t)(s | (uint32_t)m);
    }
    if (a > 448.0f) return (uint8_t)(s | 0x7E);
    uint32_t b = __float_as_uint(a);
    uint32_t expf_ = b >> 23;
    uint32_t mant = b & 0x7FFFFF;
    uint32_t keep = mant >> 20;
    uint32_t rest = mant & 0xFFFFF;
    if (rest > 0x80000u || (rest == 0x80000u && (keep & 1))) keep++;
    if (keep == 8) { keep = 0; expf_++; }
    int e8 = (int)expf_ - 120;
    if (e8 >= 16) return (uint8_t)(s | 0x7E);
    return (uint8_t)(s | ((uint32_t)e8 << 3) | keep);
}

__device__ inline float dec_e4m3(uint32_t b) {
    uint32_t mag = b & 0x7Fu;
    float fm = __uint_as_float((mag << 20) + (120u << 23));
    if ((mag >> 3) == 0) fm = fm * 2.0f - 0.015625f;
    return (b & 0x80u) ? -fm : fm;
}

// async global->LDS 16B (m97 recipe)
#define GLOAD16(gsrc, ldst) \
    __builtin_amdgcn_global_load_lds((const __attribute__((address_space(1))) unsigned int*)(gsrc), \
                                     (__attribute__((address_space(3))) unsigned int*)(ldst), 16, 0, 0)

// ---------------------------------------------------------------- build Xb = [cls; atom] (bf16 trunk)
__global__ void k_build_x(const float* __restrict__ atom, const float* __restrict__ cls,
                          __bf16* __restrict__ Xb) {
    int idx = blockIdx.x * 256 + threadIdx.x;
    int col = idx & (D_ - 1);
    int row = idx >> 9;
    int sr  = row & (SP - 1);
    int b   = row >> 8;
    float v = (sr == 0) ? cls[col] : atom[((size_t)(b * S_) + (sr - 1)) * D_ + col];
    Xb[idx] = (__bf16)v;
}

// ---------------------------------------------------------------- mask layout detection
__global__ void k_mask_detect(const unsigned int* __restrict__ mw, int nw, int* flag) {
    int i = blockIdx.x * 256 + threadIdx.x;
    if (i < nw && mw[i] > 1u) atomicOr(flag, 1);
}

__global__ void k_mask_prep(const void* __restrict__ mraw, const int* __restrict__ flag,
                            float* __restrict__ mskadd) {
    int i = blockIdx.x * 256 + threadIdx.x;
    int b = i >> 8, j = i & 255;
    float v = 0.0f;
    if (j > 0) {
        int src = b * S_ + (j - 1);
        bool m = (*flag) ? (((const unsigned char*)mraw)[src] != 0)
                         : (((const int*)mraw)[src] != 0);
        if (m) v = -1e30f;
    }
    mskadd[i] = v;
}

// ---------------------------------------------------------------- weight transpose+cast
__global__ __launch_bounds__(256) void k_wt(const float* __restrict__ W, __bf16* __restrict__ Wt,
                                            int K, int Mw, int mout_off,
                                            size_t in_lstride, size_t out_lstride) {
    __shared__ float T[64][65];
    int l = blockIdx.z;
    int m0 = blockIdx.x * 64, k0 = blockIdx.y * 64;
    const float* Wl = W + (size_t)l * in_lstride;
    __bf16* Wtl = Wt + (size_t)l * out_lstride;
    int tid = threadIdx.x;
    int cc = tid & 63, rr = tid >> 6;
#pragma unroll
    for (int p = 0; p < 16; p++) {
        int kk = rr + p * 4;
        T[kk][cc] = Wl[(size_t)(k0 + kk) * Mw + m0 + cc];
    }
    __syncthreads();
#pragma unroll
    for (int p = 0; p < 16; p++) {
        int mm = rr + p * 4;
        Wtl[(size_t)(mout_off + m0 + mm) * K + k0 + cc] = (__bf16)T[cc][mm];
    }
}

// ---------------------------------------------------------------- qkv bias concat
__global__ void k_bcat(const float* __restrict__ bq, const float* __restrict__ bk,
                       const float* __restrict__ bv, float* __restrict__ bqkv) {
    int i = blockIdx.x * 256 + threadIdx.x;
    int l = i / 1536, c = i % 1536;
    float v;
    if (c < 512)       v = bq[l * 512 + c];
    else if (c < 1024) v = bk[l * 512 + c - 512];
    else               v = bv[l * 512 + c - 1024];
    bqkv[i] = v;
}

// ---------------------------------------------------------------- bias repack, coalesced both sides
__global__ __launch_bounds__(256) void k_ebt5(const float* __restrict__ eb, uint8_t* __restrict__ ebt) {
    __shared__ uint8_t Ls[8 * 16 * 260];           // [h][qi][260], odd-dword qi stride
    int blk = blockIdx.x;                          // 64*16
    int b = blk >> 4, wm = blk & 15;
    int w = wm >> 2, mq = wm & 3;
    int qbase = w * 64 + mq * 16;
    int t = threadIdx.x;
    for (int qi = 0; qi < 16; qi++) {
        int q = qbase + qi;
        if (q > 0) {
            const float4* src = (const float4*)(eb + ((size_t)(b * 255) + (q - 1)) * 2040);
#pragma unroll
            for (int p = 0; p < 2; p++) {
                int idx4 = t + p * 256;
                if (idx4 < 510) {
                    float4 v = src[idx4];
                    int k  = idx4 >> 1;
                    int h0 = (idx4 & 1) * 4;
                    Ls[((h0 + 0) * 16 + qi) * 260 + k] = enc_e4m3(v.x);
                    Ls[((h0 + 1) * 16 + qi) * 260 + k] = enc_e4m3(v.y);
                    Ls[((h0 + 2) * 16 + qi) * 260 + k] = enc_e4m3(v.z);
                    Ls[((h0 + 3) * 16 + qi) * 260 + k] = enc_e4m3(v.w);
                }
            }
        }
    }
    __syncthreads();
    int cc = t >> 4, qi = t & 15;
    int q = qbase + qi;
    uint32_t* outp = (uint32_t*)ebt;
#pragma unroll
    for (int h = 0; h < 8; h++) {
#pragma unroll
        for (int tl = 0; tl < 4; tl++) {
            uint32_t d = 0;
            if (q > 0) {
#pragma unroll
                for (int nk = 0; nk < 4; nk++) {
                    int k = tl * 64 + nk * 16 + cc;
                    if (k > 0) d |= (uint32_t)Ls[(h * 16 + qi) * 260 + (k - 1)] << (nk * 8);
                }
            }
            size_t x = ((((size_t)(b * 8 + h) * 4 + tl) * 4 + w) * 4 + mq) * 256 + t;
            outp[x] = d;
        }
    }
}

// ---------------------------------------------------------------- 128x128 double-buffered MFMA GEMM, 8 waves
// Round-13 base (8 waves, ~107 regs/wave -> 16 waves/CU) + T3 minimum-2-phase pipeline
// (m230 recipe): STAGE(kt+1) issued BEFORE ds_read(kt); one vmcnt(0)+barrier per K-tile ->
// per-tile critical path = max(prefetch, compute), not the sum. 64 KB LDS, 2 blocks/CU
// (reg-limited anyway). __launch_bounds__(512,2): measured VGPR-cap rule ~256/min_waves.
// T1 XCD swizzle; T2 both-sides XOR involution; T5 setprio.
template<int GELU>
__global__ __launch_bounds__(512, 2) void k_gemm2(const __bf16* __restrict__ Ag,
                                                  const __bf16* __restrict__ Bg,
                                                  const float* __restrict__ bias,
                                                  __bf16* __restrict__ Cb,
                                                  __bf16* __restrict__ vtout,
                                                  int K, int M, int gx) {
    __shared__ __align__(16) __bf16 AS[2][128 * 64];
    __shared__ __align__(16) __bf16 BS[2][128 * 64];
    const int tid = threadIdx.x;
    const int w = tid >> 6, lane = tid & 63;
    const int wr = w >> 2, wc = w & 3;             // 2 row-groups x 4 col-groups
    const int lrow = lane & 15, lg = lane >> 4;
    const int nwg = gridDim.x, bid = blockIdx.x;
    const int swz = (bid & 7) * (nwg >> 3) + (bid >> 3);   // T1 (nwg % 8 == 0)
    const int by = swz / gx, bx = swz - by * gx;
    const int rowbase = by * 128, colbase = bx * 128;
    const int nkt = K >> 6;

#define STAGE(buf_, kt_) do {                                                              \
        _Pragma("unroll")                                                                  \
        for (int p_ = 0; p_ < 2; p_++) {                                                   \
            int s_ = tid + p_ * 512;                                                       \
            int row_ = s_ >> 3, sg_ = s_ & 7;                                              \
            GLOAD16(Ag + (size_t)(rowbase + row_) * K + (kt_) * 64 + ((sg_ ^ (row_ & 7)) << 3), \
                    &AS[buf_][s_ * 8]);                                                    \
            GLOAD16(Bg + (size_t)(colbase + row_) * K + (kt_) * 64 + ((sg_ ^ (row_ & 7)) << 3), \
                    &BS[buf_][s_ * 8]);                                                    \
        }                                                                                  \
    } while (0)

    f32x4 acc[4][2];
#pragma unroll
    for (int m = 0; m < 4; m++)
#pragma unroll
        for (int n = 0; n < 2; n++) acc[m][n] = f32x4{0.f, 0.f, 0.f, 0.f};

    // prologue: stage K-tile 0 into buf 0
    STAGE(0, 0);
    asm volatile("s_waitcnt vmcnt(0)" ::: "memory");
    __builtin_amdgcn_s_barrier();

    for (int kt = 0; kt < nkt; ++kt) {
        const int cur = kt & 1;
        // issue next-tile prefetch FIRST (overlaps with ds_read + MFMA below)
        if (kt + 1 < nkt) STAGE(cur ^ 1, kt + 1);
        __builtin_amdgcn_sched_barrier(0);

        bf16x8 aF[4][2], bF[2][2];
#pragma unroll
        for (int m = 0; m < 4; m++) {
            int arow = wr * 64 + m * 16 + lrow;
#pragma unroll
            for (int ks = 0; ks < 2; ks++) {
                int sl = (lg + ks * 4) ^ (arow & 7);
                aF[m][ks] = *(const bf16x8*)&AS[cur][arow * 64 + sl * 8];
            }
        }
#pragma unroll
        for (int n = 0; n < 2; n++) {
            int brow = wc * 32 + n * 16 + lrow;
#pragma unroll
            for (int ks = 0; ks < 2; ks++) {
                int sl = (lg + ks * 4) ^ (brow & 7);
                bF[n][ks] = *(const bf16x8*)&BS[cur][brow * 64 + sl * 8];
            }
        }
        asm volatile("s_waitcnt lgkmcnt(0)" ::: "memory");
        __builtin_amdgcn_sched_barrier(0);         // rule #18
        __builtin_amdgcn_s_setprio(1);
#pragma unroll
        for (int m = 0; m < 4; m++)
#pragma unroll
            for (int n = 0; n < 2; n++)
#pragma unroll
                for (int ks = 0; ks < 2; ks++)
                    acc[m][n] = __builtin_amdgcn_mfma_f32_16x16x32_bf16(aF[m][ks], bF[n][ks],
                                                                        acc[m][n], 0, 0, 0);
        __builtin_amdgcn_s_setprio(0);
        // drain prefetch, then block-wide barrier: buf[cur^1] ready, buf[cur] reads done
        asm volatile("s_waitcnt vmcnt(0)" ::: "memory");
        __builtin_amdgcn_s_barrier();
    }
#undef STAGE

    // ---- epilogue (bf16 out; V^T split for QKV) ----
    const bool dovt = (vtout != nullptr) && (colbase >= 1024);   // block-uniform
#pragma unroll
    for (int m = 0; m < 4; m++) {
        int row = rowbase + wr * 64 + m * 16 + lg * 4;
#pragma unroll
        for (int n = 0; n < 2; n++) {
            int col = colbase + wc * 32 + n * 16 + lrow;
            float bv = bias ? bias[col] : 0.0f;
            float v[4];
#pragma unroll
            for (int r = 0; r < 4; r++) {
                float x = acc[m][n][r] + bv;
                if (GELU) x = gelu_exact(x);
                v[r] = x;
            }
            if (dovt) {
                int hcol = col - 1024;
                int hh = hcol >> 6, d = hcol & 63;
                int bb = row >> 8, s0 = row & 255;
                u16x4 pk = { bf_bits(v[0]), bf_bits(v[1]), bf_bits(v[2]), bf_bits(v[3]) };
                *(u16x4*)&vtout[((size_t)((bb * 8 + hh) * 64 + d)) * 256 + s0] = pk;
            } else {
#pragma unroll
                for (int r = 0; r < 4; r++)
                    Cb[(size_t)(row + r) * M + col] = (__bf16)v[r];
            }
        }
    }
}

// ---------------------------------------------------------------- MFMA fused attention
// grid: 2048 blocks, XCD-swizzled. Monotone key mask -> block-uniform skip of fully-masked tiles.
__global__ __launch_bounds__(256) void k_attn(const __bf16* __restrict__ QKV,
                                              const uint8_t* __restrict__ ebt,
                                              const float* __restrict__ mskadd,
                                              const __bf16* __restrict__ Vt,
                                              __bf16* __restrict__ T) {
    __shared__ __align__(16) char Ks[8192];
    __shared__ __align__(16) char Vs[8192];
    __shared__ __align__(16) char Ps[4][2048];
    __shared__ float Ma[256];
    const int bid = blockIdx.x;
    const int swzb = (bid & 7) * 256 + (bid >> 3);     // T1, nwg = 2048
    const int bh = swzb >> 2, qt = swzb & 3;
    const int b = bh >> 3, h = bh & 7;
    const int tid = threadIdx.x, wid = tid >> 6, lane = tid & 63;
    const int g = lane >> 4, c = lane & 15;

    Ma[tid] = mskadd[(b << 8) + tid];

    bf16x8 qf[2];
    {
        const __bf16* qrow = QKV + (size_t)((b << 8) + qt * 64 + wid * 16 + c) * 1536 + h * 64;
        qf[0] = *(const bf16x8*)(qrow + g * 8);
        qf[1] = *(const bf16x8*)(qrow + 32 + g * 8);
    }

    f32x4 oacc[4];
    float m_s[4], l_s[4];
#pragma unroll
    for (int r = 0; r < 4; r++) { m_s[r] = -1e30f; l_s[r] = 0.0f; }
#pragma unroll
    for (int nd = 0; nd < 4; nd++) oacc[nd] = f32x4{0.f, 0.f, 0.f, 0.f};

    for (int t = 0; t < 4; t++) {
        const int t0 = t * 64;
        __syncthreads();
        if (t0 > 0 && Ma[t0] < -0.5f) continue;    // monotone mask: whole tile masked
#pragma unroll
        for (int p = 0; p < 2; p++) {
            int idx = tid + p * 256;
            int row = idx >> 3, c8 = idx & 7;
            int lds = row * 128 + ((c8 * 16) ^ ((row & 7) << 4));
            *(uint4*)(Ks + lds) = *(const uint4*)&QKV[(size_t)((b << 8) + t0 + row) * 1536 + 512 + h * 64 + c8 * 8];
            *(uint4*)(Vs + lds) = *(const uint4*)&Vt[((size_t)bh * 64 + row) * 256 + t0 + c8 * 8];
        }
        __syncthreads();

        bf16x8 kf[4][2], vb[4][2];
#pragma unroll
        for (int n = 0; n < 4; n++) {
            int row = n * 16 + c;
#pragma unroll
            for (int ks = 0; ks < 2; ks++) {
                int col = (g * 16 + ks * 64) ^ ((row & 7) << 4);
                kf[n][ks] = *(const bf16x8*)(Ks + row * 128 + col);
                vb[n][ks] = *(const bf16x8*)(Vs + row * 128 + col);
            }
        }

        f32x4 sa[4];
#pragma unroll
        for (int nk = 0; nk < 4; nk++) sa[nk] = f32x4{0.f, 0.f, 0.f, 0.f};
#pragma unroll
        for (int ks = 0; ks < 2; ks++)
#pragma unroll
            for (int nk = 0; nk < 4; nk++)
                sa[nk] = __builtin_amdgcn_mfma_f32_16x16x32_bf16(qf[ks], kf[nk][ks], sa[nk], 0, 0, 0);

        uint4 b4 = *(const uint4*)(ebt + ((((size_t)bh * 4 + t) * 4 + qt) * 4 + wid) * 1024 + c * 64 + g * 16);
        uint32_t bw[4] = { b4.x, b4.y, b4.z, b4.w };
        float s[4][4];                             // [nk][r]
#pragma unroll
        for (int nk = 0; nk < 4; nk++) {
            float ma = Ma[t0 + nk * 16 + c];
#pragma unroll
            for (int r = 0; r < 4; r++)
                s[nk][r] = sa[nk][r] * 0.125f + dec_e4m3((bw[r] >> (nk * 8)) & 0xFF) + ma;
        }

        float corr[4];
#pragma unroll
        for (int r = 0; r < 4; r++) {
            float tm = fmaxf(fmaxf(s[0][r], s[1][r]), fmaxf(s[2][r], s[3][r]));
#pragma unroll
            for (int off = 1; off < 16; off <<= 1)
                tm = fmaxf(tm, __shfl_xor(tm, off));
            float mnew = fmaxf(m_s[r], tm);
            corr[r] = __expf(m_s[r] - mnew);
            m_s[r] = mnew;
            float psum = 0.0f;
#pragma unroll
            for (int nk = 0; nk < 4; nk++) {
                s[nk][r] = __expf(s[nk][r] - mnew);
                psum += s[nk][r];
            }
#pragma unroll
            for (int off = 1; off < 16; off <<= 1)
                psum += __shfl_xor(psum, off);
            l_s[r] = l_s[r] * corr[r] + psum;
        }
#pragma unroll
        for (int nd = 0; nd < 4; nd++)
#pragma unroll
            for (int r = 0; r < 4; r++)
                oacc[nd][r] *= corr[r];

        char* psw = Ps[wid];
#pragma unroll
        for (int r = 0; r < 4; r++) {
            int qs = g * 4 + r;
#pragma unroll
            for (int nk = 0; nk < 4; nk++)
                *(__bf16*)(psw + qs * 128 + ((nk * 32 + c * 2) ^ ((qs & 7) << 4))) = (__bf16)s[nk][r];
        }
        bf16x8 pa[2];
#pragma unroll
        for (int ks = 0; ks < 2; ks++)
            pa[ks] = *(const bf16x8*)(psw + c * 128 + ((g * 16 + ks * 64) ^ ((c & 7) << 4)));
#pragma unroll
        for (int nd = 0; nd < 4; nd++)
#pragma unroll
            for (int ks = 0; ks < 2; ks++)
                oacc[nd] = __builtin_amdgcn_mfma_f32_16x16x32_bf16(pa[ks], vb[nd][ks], oacc[nd], 0, 0, 0);
    }

#pragma unroll
    for (int r = 0; r < 4; r++) {
        float inv = 1.0f / l_s[r];
        size_t rowb = (size_t)((b << 8) + qt * 64 + wid * 16 + g * 4 + r) * 512 + h * 64 + c;
#pragma unroll
        for (int nd = 0; nd < 4; nd++)
            T[rowb + nd * 16] = (__bf16)(oacc[nd][r] * inv);
    }
}

// ---------------------------------------------------------------- fused residual + LayerNorm (bf16 trunk)
__global__ __launch_bounds__(256) void k_ln3(const __bf16* __restrict__ Ob,
                                             __bf16* __restrict__ Xb,
                                             const float* __restrict__ g,
                                             const float* __restrict__ bb) {
    __shared__ float red[4];
    int row = blockIdx.x, t = threadIdx.x;
    size_t base = (size_t)row * D_;
    uint ov = *(const uint*)&Ob[base + 2 * t];
    uint xv = *(const uint*)&Xb[base + 2 * t];
    float v0 = bf_val((unsigned short)xv) + bf_val((unsigned short)ov);
    float v1 = bf_val((unsigned short)(xv >> 16)) + bf_val((unsigned short)(ov >> 16));
    float s = wave_sum(v0 + v1);
    if ((t & 63) == 0) red[t >> 6] = s;
    __syncthreads();
    float mean = (red[0] + red[1] + red[2] + red[3]) * (1.0f / D_);
    float d0 = v0 - mean, d1 = v1 - mean;
    float s2 = wave_sum(d0 * d0 + d1 * d1);
    __syncthreads();
    if ((t & 63) == 0) red[t >> 6] = s2;
    __syncthreads();
    float var = (red[0] + red[1] + red[2] + red[3]) * (1.0f / D_);
    float rr = rsqrtf(var + EPS);
    float2 gv = *(const float2*)&g[2 * t];
    float2 bv = *(const float2*)&bb[2 * t];
    float o0 = d0 * rr * gv.x + bv.x;
    float o1 = d1 * rr * gv.y + bv.y;
    uint pk = (uint)bf_bits(o0) | ((uint)bf_bits(o1) << 16);
    *(uint*)&Xb[base + 2 * t] = pk;
}

// ---------------------------------------------------------------- MLP head on CLS (bf16 trunk in)
__global__ __launch_bounds__(256) void k_head(const __bf16* __restrict__ Xb,
                                              const float* __restrict__ W1,
                                              const float* __restrict__ b1,
                                              const float* __restrict__ W2,
                                              const float* __restrict__ b2,
                                              float* __restrict__ out) {
    __shared__ float cls[D_];
    __shared__ float red[4];
    int b = blockIdx.x, t = threadIdx.x;
    size_t base = (size_t)(b << 8) * D_;
    cls[t]       = (float)Xb[base + t];
    cls[t + 256] = (float)Xb[base + t + 256];
    __syncthreads();
    float acc = 0.0f;
    for (int d = 0; d < D_; d++) acc = fmaf(cls[d], W1[(size_t)d * HID_ + t], acc);
    acc += b1[t];
    float hsum = wave_sum(gelu_exact(acc) * W2[t]);
    if ((t & 63) == 0) red[t >> 6] = hsum;
    __syncthreads();
    if (t == 0) out[b] = red[0] + red[1] + red[2] + red[3] + b2[0];
}

// ---------------------------------------------------------------- launch
extern "C" void kernel_launch(void* const* d_in, const int* in_sizes, int n_in,
                              void* d_out, int out_size, void* d_ws, size_t ws_size,
                              hipStream_t stream) {
    const float* atom = (const float*)d_in[0];
    const float* eb   = (const float*)d_in[1];
    const void*  mraw = d_in[2];
    const float* cls  = (const float*)d_in[3];
    const float* Wq = (const float*)d_in[4];  const float* bq = (const float*)d_in[5];
    const float* Wk = (const float*)d_in[6];  const float* bk = (const float*)d_in[7];
    const float* Wv = (const float*)d_in[8];  const float* bv = (const float*)d_in[9];
    const float* Wo = (const float*)d_in[10]; const float* bo = (const float*)d_in[11];
    const float* g1 = (const float*)d_in[12]; const float* be1 = (const float*)d_in[13];
    const float* W1 = (const float*)d_in[14]; const float* b1 = (const float*)d_in[15];
    const float* W2 = (const float*)d_in[16]; const float* b2 = (const float*)d_in[17];
    const float* g2 = (const float*)d_in[18]; const float* be2 = (const float*)d_in[19];
    const float* hW1 = (const float*)d_in[20]; const float* hb1 = (const float*)d_in[21];
    const float* hW2 = (const float*)d_in[22]; const float* hb2 = (const float*)d_in[23];
    float* out = (float*)d_out;

    // ---- workspace layout ----
    char* p = (char*)d_ws;
    __bf16* Xb    = (__bf16*)p;                p += (size_t)N_ * D_ * 2;        // bf16 residual trunk
    __bf16* Vt    = (__bf16*)p;                p += (size_t)N_ * D_ * 2;        // V^T (QKV->attn)
    __bf16* Ob    = (__bf16*)p;                p += (size_t)N_ * D_ * 2;        // GEMM bf16 out (O/FFN2 -> ln3)
    char*   R     = p;                         p += (size_t)N_ * FF_ * 2;
    __bf16* QKVb  = (__bf16*)R;                                                 // [N][1536]
    __bf16* Tb    = (__bf16*)(R + (size_t)N_ * 1536 * 2);                       // [N][512]
    __bf16* Hb    = (__bf16*)R;                                                 // [N][2048]
    uint8_t* ebt  = (uint8_t*)p;               p += (size_t)B_ * H_ * SP * SP;  // fragment-layout fp8
    __bf16* Wqkvt = (__bf16*)p;                p += (size_t)L_ * 1536 * 512 * 2;
    __bf16* Wot   = (__bf16*)p;                p += (size_t)L_ * 512 * 512 * 2;
    __bf16* W1t   = (__bf16*)p;                p += (size_t)L_ * 2048 * 512 * 2;
    __bf16* W2t   = (__bf16*)p;                p += (size_t)L_ * 512 * 2048 * 2;
    float*  bqkv  = (float*)p;                 p += (size_t)L_ * 1536 * 4;
    float*  mskadd= (float*)p;                 p += (size_t)B_ * SP * 4;
    int* flag = (int*)p;

    // ---- prep ----
    hipMemsetAsync(flag, 0, 4, stream);
    k_mask_detect<<<16, 256, 0, stream>>>((const unsigned int*)mraw, (B_ * S_) / 4, flag);
    k_mask_prep<<<(B_ * SP) / 256, 256, 0, stream>>>(mraw, flag, mskadd);
    k_bcat<<<(L_ * 1536) / 256, 256, 0, stream>>>(bq, bk, bv, bqkv);
    k_wt<<<dim3(8, 8, L_),  256, 0, stream>>>(Wq, Wqkvt, 512, 512, 0,    262144, 786432);
    k_wt<<<dim3(8, 8, L_),  256, 0, stream>>>(Wk, Wqkvt, 512, 512, 512,  262144, 786432);
    k_wt<<<dim3(8, 8, L_),  256, 0, stream>>>(Wv, Wqkvt, 512, 512, 1024, 262144, 786432);
    k_wt<<<dim3(8, 8, L_),  256, 0, stream>>>(Wo, Wot,   512, 512, 0,    262144, 262144);
    k_wt<<<dim3(32, 8, L_), 256, 0, stream>>>(W1, W1t,   512, 2048, 0,   1048576, 1048576);
    k_wt<<<dim3(8, 32, L_), 256, 0, stream>>>(W2, W2t,   2048, 512, 0,   1048576, 1048576);
    k_ebt5<<<B_ * 16, 256, 0, stream>>>(eb, ebt);
    k_build_x<<<(N_ * D_) / 256, 256, 0, stream>>>(atom, cls, Xb);

    for (int l = 0; l < L_; l++) {
        k_gemm2<0><<<1536, 512, 0, stream>>>(Xb, Wqkvt + (size_t)l * 786432, bqkv + l * 1536,
                                             QKVb, Vt, 512, 1536, 12);
        k_attn<<<B_ * H_ * 4, 256, 0, stream>>>(QKVb, ebt, mskadd, Vt, Tb);
        k_gemm2<0><<<512, 512, 0, stream>>>(Tb, Wot + (size_t)l * 262144, bo + l * 512,
                                            Ob, nullptr, 512, 512, 4);
        k_ln3<<<N_, 256, 0, stream>>>(Ob, Xb, g1 + l * D_, be1 + l * D_);
        k_gemm2<1><<<2048, 512, 0, stream>>>(Xb, W1t + (size_t)l * 1048576, b1 + l * FF_,
                                             Hb, nullptr, 512, 2048, 16);
        k_gemm2<0><<<512, 512, 0, stream>>>(Hb, W2t + (size_t)l * 1048576, b2 + l * D_,
                                            Ob, nullptr, 2048, 512, 4);
        k_ln3<<<N_, 256, 0, stream>>>(Ob, Xb, g2 + l * D_, be2 + l * D_);
    }
    k_head<<<B_, 256, 0, stream>>>(Xb, hW1, hb1, hW2, hb2, out);
}

// Round 15
// 1428.763 us; speedup vs baseline: 5.0431x; 1.0098x over previous
//
#include <hip/hip_runtime.h>
#include <math.h>
#include <stdint.h>

#define B_   64
#define S_   255
#define SP   256
#define D_   512
#define H_   8
#define L_   6
#define FF_  2048
#define HID_ 256
#define N_   (B_*SP)       // 16384 rows
#define EPS  1e-5f

using bf16x8 = __bf16 __attribute__((ext_vector_type(8)));
using f32x4  = float __attribute__((ext_vector_type(4)));
using u16x4  = unsigned short __attribute__((ext_vector_type(4)));

// ---------------------------------------------------------------- utilities
__device__ inline float wave_sum(float v) {
#pragma unroll
    for (int off = 32; off; off >>= 1) v += __shfl_xor(v, off);
    return v;
}

// fast exact-erf gelu: A&S 7.1.26 polynomial, |erf err| <= 1.5e-7
__device__ inline float gelu_exact(float x) {
    float z  = fabsf(x) * 0.70710678118654752f;
    float tt = __builtin_amdgcn_rcpf(fmaf(0.3275911f, z, 1.0f));
    float poly = tt * (0.254829592f + tt * (-0.284496736f + tt * (1.421413741f +
                 tt * (-1.453152027f + tt * 1.061405429f))));
    float er = 1.0f - poly * __expf(-z * z);
    er = copysignf(er, x);
    return 0.5f * x * (1.0f + er);
}

__device__ inline unsigned short bf_bits(float x) {
    __bf16 h = (__bf16)x;
    return *(unsigned short*)&h;
}

__device__ inline float bf_val(unsigned short u) {
    __bf16 h = *(__bf16*)&u;
    return (float)h;
}

// fp8 e4m3fn encode (RNE) / decode
__device__ inline uint8_t enc_e4m3(float f) {
    uint32_t u = __float_as_uint(f);
    uint32_t s = (u >> 24) & 0x80u;
    float a = fabsf(f);
    if (a < 0.015625f) {
        int m = (int)rintf(a * 512.0f);
        if (m >= 8) return (uint8_t)(s | 0x08);
        return (uint8_t)(s | (uint32_t)m);
    }
    if (a > 448.0f) return (uint8_t)(s | 0x7E);
    uint32_t b = __float_as_uint(a);
    uint32_t expf_ = b >> 23;
    uint32_t mant = b & 0x7FFFFF;
    uint32_t keep = mant >> 20;
    uint32_t rest = mant & 0xFFFFF;
    if (rest > 0x80000u || (rest == 0x80000u && (keep & 1))) keep++;
    if (keep == 8) { keep = 0; expf_++; }
    int e8 = (int)expf_ - 120;
    if (e8 >= 16) return (uint8_t)(s | 0x7E);
    return (uint8_t)(s | ((uint32_t)e8 << 3) | keep);
}

__device__ inline float dec_e4m3(uint32_t b) {
    uint32_t mag = b & 0x7Fu;
    float fm = __uint_as_float((mag << 20) + (120u << 23));
    if ((mag >> 3) == 0) fm = fm * 2.0f - 0.015625f;
    return (b & 0x80u) ? -fm : fm;
}

// async global->LDS 16B (m97 recipe)
#define GLOAD16(gsrc, ldst) \
    __builtin_amdgcn_global_load_lds((const __attribute__((address_space(1))) unsigned int*)(gsrc), \
                                     (__attribute__((address_space(3))) unsigned int*)(ldst), 16, 0, 0)

// ---------------------------------------------------------------- build Xb = [cls; atom] (bf16 trunk)
__global__ void k_build_x(const float* __restrict__ atom, const float* __restrict__ cls,
                          __bf16* __restrict__ Xb) {
    int idx = blockIdx.x * 256 + threadIdx.x;
    int col = idx & (D_ - 1);
    int row = idx >> 9;
    int sr  = row & (SP - 1);
    int b   = row >> 8;
    float v = (sr == 0) ? cls[col] : atom[((size_t)(b * S_) + (sr - 1)) * D_ + col];
    Xb[idx] = (__bf16)v;
}

// ---------------------------------------------------------------- mask layout detection
__global__ void k_mask_detect(const unsigned int* __restrict__ mw, int nw, int* flag) {
    int i = blockIdx.x * 256 + threadIdx.x;
    if (i < nw && mw[i] > 1u) atomicOr(flag, 1);
}

__global__ void k_mask_prep(const void* __restrict__ mraw, const int* __restrict__ flag,
                            float* __restrict__ mskadd) {
    int i = blockIdx.x * 256 + threadIdx.x;
    int b = i >> 8, j = i & 255;
    float v = 0.0f;
    if (j > 0) {
        int src = b * S_ + (j - 1);
        bool m = (*flag) ? (((const unsigned char*)mraw)[src] != 0)
                         : (((const int*)mraw)[src] != 0);
        if (m) v = -1e30f;
    }
    mskadd[i] = v;
}

// ---------------------------------------------------------------- weight transpose+cast
__global__ __launch_bounds__(256) void k_wt(const float* __restrict__ W, __bf16* __restrict__ Wt,
                                            int K, int Mw, int mout_off,
                                            size_t in_lstride, size_t out_lstride) {
    __shared__ float T[64][65];
    int l = blockIdx.z;
    int m0 = blockIdx.x * 64, k0 = blockIdx.y * 64;
    const float* Wl = W + (size_t)l * in_lstride;
    __bf16* Wtl = Wt + (size_t)l * out_lstride;
    int tid = threadIdx.x;
    int cc = tid & 63, rr = tid >> 6;
#pragma unroll
    for (int p = 0; p < 16; p++) {
        int kk = rr + p * 4;
        T[kk][cc] = Wl[(size_t)(k0 + kk) * Mw + m0 + cc];
    }
    __syncthreads();
#pragma unroll
    for (int p = 0; p < 16; p++) {
        int mm = rr + p * 4;
        Wtl[(size_t)(mout_off + m0 + mm) * K + k0 + cc] = (__bf16)T[cc][mm];
    }
}

// ---------------------------------------------------------------- qkv bias concat
__global__ void k_bcat(const float* __restrict__ bq, const float* __restrict__ bk,
                       const float* __restrict__ bv, float* __restrict__ bqkv) {
    int i = blockIdx.x * 256 + threadIdx.x;
    int l = i / 1536, c = i % 1536;
    float v;
    if (c < 512)       v = bq[l * 512 + c];
    else if (c < 1024) v = bk[l * 512 + c - 512];
    else               v = bv[l * 512 + c - 1024];
    bqkv[i] = v;
}

// ---------------------------------------------------------------- bias repack, coalesced both sides
__global__ __launch_bounds__(256) void k_ebt5(const float* __restrict__ eb, uint8_t* __restrict__ ebt) {
    __shared__ uint8_t Ls[8 * 16 * 260];           // [h][qi][260], odd-dword qi stride
    int blk = blockIdx.x;                          // 64*16
    int b = blk >> 4, wm = blk & 15;
    int w = wm >> 2, mq = wm & 3;
    int qbase = w * 64 + mq * 16;
    int t = threadIdx.x;
    for (int qi = 0; qi < 16; qi++) {
        int q = qbase + qi;
        if (q > 0) {
            const float4* src = (const float4*)(eb + ((size_t)(b * 255) + (q - 1)) * 2040);
#pragma unroll
            for (int p = 0; p < 2; p++) {
                int idx4 = t + p * 256;
                if (idx4 < 510) {
                    float4 v = src[idx4];
                    int k  = idx4 >> 1;
                    int h0 = (idx4 & 1) * 4;
                    Ls[((h0 + 0) * 16 + qi) * 260 + k] = enc_e4m3(v.x);
                    Ls[((h0 + 1) * 16 + qi) * 260 + k] = enc_e4m3(v.y);
                    Ls[((h0 + 2) * 16 + qi) * 260 + k] = enc_e4m3(v.z);
                    Ls[((h0 + 3) * 16 + qi) * 260 + k] = enc_e4m3(v.w);
                }
            }
        }
    }
    __syncthreads();
    int cc = t >> 4, qi = t & 15;
    int q = qbase + qi;
    uint32_t* outp = (uint32_t*)ebt;
#pragma unroll
    for (int h = 0; h < 8; h++) {
#pragma unroll
        for (int tl = 0; tl < 4; tl++) {
            uint32_t d = 0;
            if (q > 0) {
#pragma unroll
                for (int nk = 0; nk < 4; nk++) {
                    int k = tl * 64 + nk * 16 + cc;
                    if (k > 0) d |= (uint32_t)Ls[(h * 16 + qi) * 260 + (k - 1)] << (nk * 8);
                }
            }
            size_t x = ((((size_t)(b * 8 + h) * 4 + tl) * 4 + w) * 4 + mq) * 256 + t;
            outp[x] = d;
        }
    }
}

// ---------------------------------------------------------------- 64x128 single-buffer MFMA GEMM, 4 waves
// Rounds 9-14 diagnosis: skinny GEMMs are LATENCY-bound; binding constraint = blocks/CU.
// Tile 64x128, 4 waves (2x2, per-wave 32x64): acc 32 + frags 48 ~= 100 VGPR -> 4 waves/SIMD,
// 24 KB LDS -> 4 independent blocks/CU (2x round-14) -> m114 cross-block overlap covers the
// per-tile vmcnt/barrier drains. Larger grids (1024-4096 blocks) kill tail effects.
// __launch_bounds__(256,2): measured VGPR-cap rule ~256/min_waves (do NOT raise min_waves).
// T1 XCD swizzle; T2 both-sides XOR involution; T5 setprio.
template<int GELU>
__global__ __launch_bounds__(256, 2) void k_gemm2(const __bf16* __restrict__ Ag,
                                                  const __bf16* __restrict__ Bg,
                                                  const float* __restrict__ bias,
                                                  __bf16* __restrict__ Cb,
                                                  __bf16* __restrict__ vtout,
                                                  int K, int M, int gx) {
    __shared__ __align__(16) __bf16 AS[64 * 64];
    __shared__ __align__(16) __bf16 BS[128 * 64];
    const int tid = threadIdx.x;
    const int w = tid >> 6, lane = tid & 63;
    const int wr = w >> 1, wc = w & 1;             // 2 row-groups x 2 col-groups
    const int lrow = lane & 15, lg = lane >> 4;
    const int nwg = gridDim.x, bid = blockIdx.x;
    const int swz = (bid & 7) * (nwg >> 3) + (bid >> 3);   // T1 (nwg % 8 == 0)
    const int by = swz / gx, bx = swz - by * gx;
    const int rowbase = by * 64, colbase = bx * 128;
    const int nkt = K >> 6;

    f32x4 acc[2][4];
#pragma unroll
    for (int m = 0; m < 2; m++)
#pragma unroll
        for (int n = 0; n < 4; n++) acc[m][n] = f32x4{0.f, 0.f, 0.f, 0.f};

    for (int kt = 0; kt < nkt; ++kt) {
        if (kt) __builtin_amdgcn_s_barrier();      // prior tile's ds_reads done
        __builtin_amdgcn_sched_barrier(0);
        // stage A (512 slots of 16B) + B (1024 slots)
#pragma unroll
        for (int p = 0; p < 2; p++) {
            int s = tid + p * 256;
            int row = s >> 3, sg = s & 7;
            GLOAD16(Ag + (size_t)(rowbase + row) * K + kt * 64 + ((sg ^ (row & 7)) << 3), &AS[s * 8]);
        }
#pragma unroll
        for (int p = 0; p < 4; p++) {
            int s = tid + p * 256;
            int row = s >> 3, sg = s & 7;
            GLOAD16(Bg + (size_t)(colbase + row) * K + kt * 64 + ((sg ^ (row & 7)) << 3), &BS[s * 8]);
        }
        asm volatile("s_waitcnt vmcnt(0)" ::: "memory");
        __builtin_amdgcn_s_barrier();

        bf16x8 aF[2][2], bF[4][2];
#pragma unroll
        for (int m = 0; m < 2; m++) {
            int arow = wr * 32 + m * 16 + lrow;
#pragma unroll
            for (int ks = 0; ks < 2; ks++) {
                int sl = (lg + ks * 4) ^ (arow & 7);
                aF[m][ks] = *(const bf16x8*)&AS[arow * 64 + sl * 8];
            }
        }
#pragma unroll
        for (int n = 0; n < 4; n++) {
            int brow = wc * 64 + n * 16 + lrow;
#pragma unroll
            for (int ks = 0; ks < 2; ks++) {
                int sl = (lg + ks * 4) ^ (brow & 7);
                bF[n][ks] = *(const bf16x8*)&BS[brow * 64 + sl * 8];
            }
        }
        asm volatile("s_waitcnt lgkmcnt(0)" ::: "memory");
        __builtin_amdgcn_sched_barrier(0);         // rule #18
        __builtin_amdgcn_s_setprio(1);
#pragma unroll
        for (int m = 0; m < 2; m++)
#pragma unroll
            for (int n = 0; n < 4; n++)
#pragma unroll
                for (int ks = 0; ks < 2; ks++)
                    acc[m][n] = __builtin_amdgcn_mfma_f32_16x16x32_bf16(aF[m][ks], bF[n][ks],
                                                                        acc[m][n], 0, 0, 0);
        __builtin_amdgcn_s_setprio(0);
    }

    // ---- epilogue (bf16 out; V^T split for QKV) ----
    const bool dovt = (vtout != nullptr) && (colbase >= 1024);   // block-uniform
#pragma unroll
    for (int m = 0; m < 2; m++) {
        int row = rowbase + wr * 32 + m * 16 + lg * 4;
#pragma unroll
        for (int n = 0; n < 4; n++) {
            int col = colbase + wc * 64 + n * 16 + lrow;
            float bv = bias ? bias[col] : 0.0f;
            float v[4];
#pragma unroll
            for (int r = 0; r < 4; r++) {
                float x = acc[m][n][r] + bv;
                if (GELU) x = gelu_exact(x);
                v[r] = x;
            }
            if (dovt) {
                int hcol = col - 1024;
                int hh = hcol >> 6, d = hcol & 63;
                int bb = row >> 8, s0 = row & 255;
                u16x4 pk = { bf_bits(v[0]), bf_bits(v[1]), bf_bits(v[2]), bf_bits(v[3]) };
                *(u16x4*)&vtout[((size_t)((bb * 8 + hh) * 64 + d)) * 256 + s0] = pk;
            } else {
#pragma unroll
                for (int r = 0; r < 4; r++)
                    Cb[(size_t)(row + r) * M + col] = (__bf16)v[r];
            }
        }
    }
}

// ---------------------------------------------------------------- MFMA fused attention
// grid: 2048 blocks, XCD-swizzled. Monotone key mask -> block-uniform skip of fully-masked tiles.
__global__ __launch_bounds__(256) void k_attn(const __bf16* __restrict__ QKV,
                                              const uint8_t* __restrict__ ebt,
                                              const float* __restrict__ mskadd,
                                              const __bf16* __restrict__ Vt,
                                              __bf16* __restrict__ T) {
    __shared__ __align__(16) char Ks[8192];
    __shared__ __align__(16) char Vs[8192];
    __shared__ __align__(16) char Ps[4][2048];
    __shared__ float Ma[256];
    const int bid = blockIdx.x;
    const int swzb = (bid & 7) * 256 + (bid >> 3);     // T1, nwg = 2048
    const int bh = swzb >> 2, qt = swzb & 3;
    const int b = bh >> 3, h = bh & 7;
    const int tid = threadIdx.x, wid = tid >> 6, lane = tid & 63;
    const int g = lane >> 4, c = lane & 15;

    Ma[tid] = mskadd[(b << 8) + tid];

    bf16x8 qf[2];
    {
        const __bf16* qrow = QKV + (size_t)((b << 8) + qt * 64 + wid * 16 + c) * 1536 + h * 64;
        qf[0] = *(const bf16x8*)(qrow + g * 8);
        qf[1] = *(const bf16x8*)(qrow + 32 + g * 8);
    }

    f32x4 oacc[4];
    float m_s[4], l_s[4];
#pragma unroll
    for (int r = 0; r < 4; r++) { m_s[r] = -1e30f; l_s[r] = 0.0f; }
#pragma unroll
    for (int nd = 0; nd < 4; nd++) oacc[nd] = f32x4{0.f, 0.f, 0.f, 0.f};

    for (int t = 0; t < 4; t++) {
        const int t0 = t * 64;
        __syncthreads();
        if (t0 > 0 && Ma[t0] < -0.5f) continue;    // monotone mask: whole tile masked
#pragma unroll
        for (int p = 0; p < 2; p++) {
            int idx = tid + p * 256;
            int row = idx >> 3, c8 = idx & 7;
            int lds = row * 128 + ((c8 * 16) ^ ((row & 7) << 4));
            *(uint4*)(Ks + lds) = *(const uint4*)&QKV[(size_t)((b << 8) + t0 + row) * 1536 + 512 + h * 64 + c8 * 8];
            *(uint4*)(Vs + lds) = *(const uint4*)&Vt[((size_t)bh * 64 + row) * 256 + t0 + c8 * 8];
        }
        __syncthreads();

        bf16x8 kf[4][2], vb[4][2];
#pragma unroll
        for (int n = 0; n < 4; n++) {
            int row = n * 16 + c;
#pragma unroll
            for (int ks = 0; ks < 2; ks++) {
                int col = (g * 16 + ks * 64) ^ ((row & 7) << 4);
                kf[n][ks] = *(const bf16x8*)(Ks + row * 128 + col);
                vb[n][ks] = *(const bf16x8*)(Vs + row * 128 + col);
            }
        }

        f32x4 sa[4];
#pragma unroll
        for (int nk = 0; nk < 4; nk++) sa[nk] = f32x4{0.f, 0.f, 0.f, 0.f};
#pragma unroll
        for (int ks = 0; ks < 2; ks++)
#pragma unroll
            for (int nk = 0; nk < 4; nk++)
                sa[nk] = __builtin_amdgcn_mfma_f32_16x16x32_bf16(qf[ks], kf[nk][ks], sa[nk], 0, 0, 0);

        uint4 b4 = *(const uint4*)(ebt + ((((size_t)bh * 4 + t) * 4 + qt) * 4 + wid) * 1024 + c * 64 + g * 16);
        uint32_t bw[4] = { b4.x, b4.y, b4.z, b4.w };
        float s[4][4];                             // [nk][r]
#pragma unroll
        for (int nk = 0; nk < 4; nk++) {
            float ma = Ma[t0 + nk * 16 + c];
#pragma unroll
            for (int r = 0; r < 4; r++)
                s[nk][r] = sa[nk][r] * 0.125f + dec_e4m3((bw[r] >> (nk * 8)) & 0xFF) + ma;
        }

        float corr[4];
#pragma unroll
        for (int r = 0; r < 4; r++) {
            float tm = fmaxf(fmaxf(s[0][r], s[1][r]), fmaxf(s[2][r], s[3][r]));
#pragma unroll
            for (int off = 1; off < 16; off <<= 1)
                tm = fmaxf(tm, __shfl_xor(tm, off));
            float mnew = fmaxf(m_s[r], tm);
            corr[r] = __expf(m_s[r] - mnew);
            m_s[r] = mnew;
            float psum = 0.0f;
#pragma unroll
            for (int nk = 0; nk < 4; nk++) {
                s[nk][r] = __expf(s[nk][r] - mnew);
                psum += s[nk][r];
            }
#pragma unroll
            for (int off = 1; off < 16; off <<= 1)
                psum += __shfl_xor(psum, off);
            l_s[r] = l_s[r] * corr[r] + psum;
        }
#pragma unroll
        for (int nd = 0; nd < 4; nd++)
#pragma unroll
            for (int r = 0; r < 4; r++)
                oacc[nd][r] *= corr[r];

        char* psw = Ps[wid];
#pragma unroll
        for (int r = 0; r < 4; r++) {
            int qs = g * 4 + r;
#pragma unroll
            for (int nk = 0; nk < 4; nk++)
                *(__bf16*)(psw + qs * 128 + ((nk * 32 + c * 2) ^ ((qs & 7) << 4))) = (__bf16)s[nk][r];
        }
        bf16x8 pa[2];
#pragma unroll
        for (int ks = 0; ks < 2; ks++)
            pa[ks] = *(const bf16x8*)(psw + c * 128 + ((g * 16 + ks * 64) ^ ((c & 7) << 4)));
#pragma unroll
        for (int nd = 0; nd < 4; nd++)
#pragma unroll
            for (int ks = 0; ks < 2; ks++)
                oacc[nd] = __builtin_amdgcn_mfma_f32_16x16x32_bf16(pa[ks], vb[nd][ks], oacc[nd], 0, 0, 0);
    }

#pragma unroll
    for (int r = 0; r < 4; r++) {
        float inv = 1.0f / l_s[r];
        size_t rowb = (size_t)((b << 8) + qt * 64 + wid * 16 + g * 4 + r) * 512 + h * 64 + c;
#pragma unroll
        for (int nd = 0; nd < 4; nd++)
            T[rowb + nd * 16] = (__bf16)(oacc[nd][r] * inv);
    }
}

// ---------------------------------------------------------------- fused residual + LayerNorm (bf16 trunk)
__global__ __launch_bounds__(256) void k_ln3(const __bf16* __restrict__ Ob,
                                             __bf16* __restrict__ Xb,
                                             const float* __restrict__ g,
                                             const float* __restrict__ bb) {
    __shared__ float red[4];
    int row = blockIdx.x, t = threadIdx.x;
    size_t base = (size_t)row * D_;
    uint ov = *(const uint*)&Ob[base + 2 * t];
    uint xv = *(const uint*)&Xb[base + 2 * t];
    float v0 = bf_val((unsigned short)xv) + bf_val((unsigned short)ov);
    float v1 = bf_val((unsigned short)(xv >> 16)) + bf_val((unsigned short)(ov >> 16));
    float s = wave_sum(v0 + v1);
    if ((t & 63) == 0) red[t >> 6] = s;
    __syncthreads();
    float mean = (red[0] + red[1] + red[2] + red[3]) * (1.0f / D_);
    float d0 = v0 - mean, d1 = v1 - mean;
    float s2 = wave_sum(d0 * d0 + d1 * d1);
    __syncthreads();
    if ((t & 63) == 0) red[t >> 6] = s2;
    __syncthreads();
    float var = (red[0] + red[1] + red[2] + red[3]) * (1.0f / D_);
    float rr = rsqrtf(var + EPS);
    float2 gv = *(const float2*)&g[2 * t];
    float2 bv = *(const float2*)&bb[2 * t];
    float o0 = d0 * rr * gv.x + bv.x;
    float o1 = d1 * rr * gv.y + bv.y;
    uint pk = (uint)bf_bits(o0) | ((uint)bf_bits(o1) << 16);
    *(uint*)&Xb[base + 2 * t] = pk;
}

// ---------------------------------------------------------------- MLP head on CLS (bf16 trunk in)
__global__ __launch_bounds__(256) void k_head(const __bf16* __restrict__ Xb,
                                              const float* __restrict__ W1,
                                              const float* __restrict__ b1,
                                              const float* __restrict__ W2,
                                              const float* __restrict__ b2,
                                              float* __restrict__ out) {
    __shared__ float cls[D_];
    __shared__ float red[4];
    int b = blockIdx.x, t = threadIdx.x;
    size_t base = (size_t)(b << 8) * D_;
    cls[t]       = (float)Xb[base + t];
    cls[t + 256] = (float)Xb[base + t + 256];
    __syncthreads();
    float acc = 0.0f;
    for (int d = 0; d < D_; d++) acc = fmaf(cls[d], W1[(size_t)d * HID_ + t], acc);
    acc += b1[t];
    float hsum = wave_sum(gelu_exact(acc) * W2[t]);
    if ((t & 63) == 0) red[t >> 6] = hsum;
    __syncthreads();
    if (t == 0) out[b] = red[0] + red[1] + red[2] + red[3] + b2[0];
}

// ---------------------------------------------------------------- launch
extern "C" void kernel_launch(void* const* d_in, const int* in_sizes, int n_in,
                              void* d_out, int out_size, void* d_ws, size_t ws_size,
                              hipStream_t stream) {
    const float* atom = (const float*)d_in[0];
    const float* eb   = (const float*)d_in[1];
    const void*  mraw = d_in[2];
    const float* cls  = (const float*)d_in[3];
    const float* Wq = (const float*)d_in[4];  const float* bq = (const float*)d_in[5];
    const float* Wk = (const float*)d_in[6];  const float* bk = (const float*)d_in[7];
    const float* Wv = (const float*)d_in[8];  const float* bv = (const float*)d_in[9];
    const float* Wo = (const float*)d_in[10]; const float* bo = (const float*)d_in[11];
    const float* g1 = (const float*)d_in[12]; const float* be1 = (const float*)d_in[13];
    const float* W1 = (const float*)d_in[14]; const float* b1 = (const float*)d_in[15];
    const float* W2 = (const float*)d_in[16]; const float* b2 = (const float*)d_in[17];
    const float* g2 = (const float*)d_in[18]; const float* be2 = (const float*)d_in[19];
    const float* hW1 = (const float*)d_in[20]; const float* hb1 = (const float*)d_in[21];
    const float* hW2 = (const float*)d_in[22]; const float* hb2 = (const float*)d_in[23];
    float* out = (float*)d_out;

    // ---- workspace layout ----
    char* p = (char*)d_ws;
    __bf16* Xb    = (__bf16*)p;                p += (size_t)N_ * D_ * 2;        // bf16 residual trunk
    __bf16* Vt    = (__bf16*)p;                p += (size_t)N_ * D_ * 2;        // V^T (QKV->attn)
    __bf16* Ob    = (__bf16*)p;                p += (size_t)N_ * D_ * 2;        // GEMM bf16 out (O/FFN2 -> ln3)
    char*   R     = p;                         p += (size_t)N_ * FF_ * 2;
    __bf16* QKVb  = (__bf16*)R;                                                 // [N][1536]
    __bf16* Tb    = (__bf16*)(R + (size_t)N_ * 1536 * 2);                       // [N][512]
    __bf16* Hb    = (__bf16*)R;                                                 // [N][2048]
    uint8_t* ebt  = (uint8_t*)p;               p += (size_t)B_ * H_ * SP * SP;  // fragment-layout fp8
    __bf16* Wqkvt = (__bf16*)p;                p += (size_t)L_ * 1536 * 512 * 2;
    __bf16* Wot   = (__bf16*)p;                p += (size_t)L_ * 512 * 512 * 2;
    __bf16* W1t   = (__bf16*)p;                p += (size_t)L_ * 2048 * 512 * 2;
    __bf16* W2t   = (__bf16*)p;                p += (size_t)L_ * 512 * 2048 * 2;
    float*  bqkv  = (float*)p;                 p += (size_t)L_ * 1536 * 4;
    float*  mskadd= (float*)p;                 p += (size_t)B_ * SP * 4;
    int* flag = (int*)p;

    // ---- prep ----
    hipMemsetAsync(flag, 0, 4, stream);
    k_mask_detect<<<16, 256, 0, stream>>>((const unsigned int*)mraw, (B_ * S_) / 4, flag);
    k_mask_prep<<<(B_ * SP) / 256, 256, 0, stream>>>(mraw, flag, mskadd);
    k_bcat<<<(L_ * 1536) / 256, 256, 0, stream>>>(bq, bk, bv, bqkv);
    k_wt<<<dim3(8, 8, L_),  256, 0, stream>>>(Wq, Wqkvt, 512, 512, 0,    262144, 786432);
    k_wt<<<dim3(8, 8, L_),  256, 0, stream>>>(Wk, Wqkvt, 512, 512, 512,  262144, 786432);
    k_wt<<<dim3(8, 8, L_),  256, 0, stream>>>(Wv, Wqkvt, 512, 512, 1024, 262144, 786432);
    k_wt<<<dim3(8, 8, L_),  256, 0, stream>>>(Wo, Wot,   512, 512, 0,    262144, 262144);
    k_wt<<<dim3(32, 8, L_), 256, 0, stream>>>(W1, W1t,   512, 2048, 0,   1048576, 1048576);
    k_wt<<<dim3(8, 32, L_), 256, 0, stream>>>(W2, W2t,   2048, 512, 0,   1048576, 1048576);
    k_ebt5<<<B_ * 16, 256, 0, stream>>>(eb, ebt);
    k_build_x<<<(N_ * D_) / 256, 256, 0, stream>>>(atom, cls, Xb);

    for (int l = 0; l < L_; l++) {
        k_gemm2<0><<<3072, 256, 0, stream>>>(Xb, Wqkvt + (size_t)l * 786432, bqkv + l * 1536,
                                             QKVb, Vt, 512, 1536, 12);
        k_attn<<<B_ * H_ * 4, 256, 0, stream>>>(QKVb, ebt, mskadd, Vt, Tb);
        k_gemm2<0><<<1024, 256, 0, stream>>>(Tb, Wot + (size_t)l * 262144, bo + l * 512,
                                             Ob, nullptr, 512, 512, 4);
        k_ln3<<<N_, 256, 0, stream>>>(Ob, Xb, g1 + l * D_, be1 + l * D_);
        k_gemm2<1><<<4096, 256, 0, stream>>>(Xb, W1t + (size_t)l * 1048576, b1 + l * FF_,
                                             Hb, nullptr, 512, 2048, 16);
        k_gemm2<0><<<1024, 256, 0, stream>>>(Hb, W2t + (size_t)l * 1048576, b2 + l * D_,
                                             Ob, nullptr, 2048, 512, 4);
        k_ln3<<<N_, 256, 0, stream>>>(Ob, Xb, g2 + l * D_, be2 + l * D_);
    }
    k_head<<<B_, 256, 0, stream>>>(Xb, hW1, hb1, hW2, hb2, out);
}